// Round 11
// baseline (266.947 us; speedup 1.0000x reference)
//
#include <hip/hip_runtime.h>
#include <hip/hip_bf16.h>

#define D 64
#define NRAT 6

typedef float f32x4 __attribute__((ext_vector_type(4)));
typedef short bf16x8 __attribute__((ext_vector_type(8)));

union FragU { uint32_t u[4]; bf16x8 v; };

__device__ __forceinline__ short f2bf(float f) {
    __hip_bfloat16 h = __float2bfloat16(f);
    union { __hip_bfloat16 h; short s; } c; c.h = h; return c.s;
}
__device__ __forceinline__ uint32_t pk2(float a, float b) {
    union { short s[2]; uint32_t u; } c; c.s[0] = f2bf(a); c.s[1] = f2bf(b); return c.u;
}

// Fused setup: (a) t<513 zero coarse counters + done flag; (b) node features
// hu/hi in bf16; (c) threads [1024,1024+73728) pack all weights to MFMA
// fragment order (bf16).
__global__ void build_setup(const int* __restrict__ uid, const int* __restrict__ iid,
                            const int* __restrict__ gender, const int* __restrict__ genres,
                            const float* __restrict__ user_emb, const float* __restrict__ item_emb,
                            const float* __restrict__ gender_emb, const float* __restrict__ genre_emb,
                            unsigned short* __restrict__ hu, unsigned short* __restrict__ hi,
                            int* __restrict__ zeroRegion,
                            const float* __restrict__ Wr_w, const float* __restrict__ Wr_wb,
                            const float* __restrict__ Ww, const float* __restrict__ Wwb,
                            const float* __restrict__ Vf, const float* __restrict__ Wf,
                            short* __restrict__ pWrW, short* __restrict__ pWrWB,
                            short* __restrict__ pWw, short* __restrict__ pWwb,
                            short* __restrict__ pVf, short* __restrict__ pWf,
                            int NU, int NI) {
    int t = blockIdx.x * blockDim.x + threadIdx.x;
    if (t < 513) zeroRegion[t] = 0;      // cntI(256) + cntU(256) + done(1)

    // weight packing on threads [1024, 1024+73728)
    int tp = t - 1024;
    if (tp >= 0 && tp < 73728) {
        const float* src; short* dst; int K; int idx;
        if      (tp < 24576) { src = Wr_w;  dst = pWrW;  K = 64;  idx = tp; }
        else if (tp < 49152) { src = Wr_wb; dst = pWrWB; K = 64;  idx = tp - 24576; }
        else if (tp < 57344) { src = Ww;    dst = pWw;   K = 128; idx = tp - 49152; }
        else if (tp < 65536) { src = Wwb;   dst = pWwb;  K = 128; idx = tp - 57344; }
        else if (tp < 69632) { src = Vf;    dst = pVf;   K = 64;  idx = tp - 65536; }
        else                 { src = Wf;    dst = pWf;   K = 64;  idx = tp - 69632; }
        int per  = 64 * K;
        int sub  = idx / per;
        int li   = idx % per;
        int e    = li & 7;
        int lane = (li >> 3) & 63;
        int frag = li >> 9;
        int nkt  = K >> 5;
        int t16  = frag / nkt, tk = frag % nkt;
        int row  = t16 * 16 + (lane & 15);
        int col  = tk * 32 + (lane >> 4) * 8 + e;
        dst[idx] = f2bf(src[((size_t)(sub * 64 + row)) * K + col]);
    }

    int total = (NU + NI) * 16;          // one float4 (4 dims) per thread
    if (t >= total) return;
    int row = t >> 4, c = t & 15;
    uint2 o;
    if (row < NU) {
        int u = uid[row], g = gender[row];
        float4 a = ((const float4*)user_emb)[(size_t)u * 16 + c];
        float4 b = ((const float4*)gender_emb)[(size_t)g * 16 + c];
        o.x = pk2(a.x + b.x, a.y + b.y); o.y = pk2(a.z + b.z, a.w + b.w);
        ((uint2*)hu)[(size_t)row * 16 + c] = o;
    } else {
        int r2 = row - NU;
        int it = iid[r2], ge = genres[r2];
        float4 a = ((const float4*)item_emb)[(size_t)it * 16 + c];
        float4 b = ((const float4*)genre_emb)[(size_t)ge * 16 + c];
        o.x = pk2(a.x + b.x, a.y + b.y); o.y = pk2(a.z + b.z, a.w + b.w);
        ((uint2*)hi)[(size_t)r2 * 16 + c] = o;
    }
}

// One pass over both edge arrays: LDS hists for items (>>8) and users (>>9).
// Last block to finish also performs both coarse scans (done flag pre-zeroed).
__global__ __launch_bounds__(256) void hist_scan(
        const int* __restrict__ edge_item, const int* __restrict__ edge_user,
        int* __restrict__ cntI, int* __restrict__ cntU, int* __restrict__ done,
        int* __restrict__ offI, int* __restrict__ offU,
        int* __restrict__ curI, int* __restrict__ curU,
        int NBI, int NBU, int E) {
    __shared__ int hI[256], hU[256];
    __shared__ int isLast;
    const int tid = threadIdx.x;
    hI[tid] = 0; hU[tid] = 0;
    __syncthreads();
    for (int i = blockIdx.x * blockDim.x + tid; i < E; i += gridDim.x * blockDim.x) {
        atomicAdd(&hI[edge_item[i] >> 8], 1);
        atomicAdd(&hU[edge_user[i] >> 9], 1);
    }
    __syncthreads();
    int vi = hI[tid], vu = hU[tid];
    if (vi) atomicAdd(&cntI[tid], vi);
    if (vu) atomicAdd(&cntU[tid], vu);
    __threadfence();
    __syncthreads();
    if (tid == 0) isLast = (atomicAdd(done, 1) == (int)gridDim.x - 1);
    __syncthreads();
    if (!isLast) return;

    // scan both directions (atomic reads guarantee visibility)
    int sI = (tid < NBI) ? atomicAdd(&cntI[tid], 0) : 0;
    int sU = (tid < NBU) ? atomicAdd(&cntU[tid], 0) : 0;
    __syncthreads();
    hI[tid] = sI; hU[tid] = sU;
    __syncthreads();
    for (int dd = 1; dd < 256; dd <<= 1) {
        int aI = (tid >= dd) ? hI[tid - dd] : 0;
        int aU = (tid >= dd) ? hU[tid - dd] : 0;
        __syncthreads();
        hI[tid] += aI; hU[tid] += aU;
        __syncthreads();
    }
    int eI = hI[tid] - sI, eU = hU[tid] - sU;
    if (tid < NBI) { offI[tid] = eI; curI[tid] = eI; }
    if (tid < NBU) { offU[tid] = eU; curU[tid] = eU; }
    if (tid == 0) { offI[NBI] = E; offU[NBU] = E; }
}

// Pass A, both directions. Record = (r*Ns + src)(20b) | dstLow(<=9b at bit 20).
__global__ __launch_bounds__(256) void multisplit_A2(
        const int* __restrict__ edge_item, const int* __restrict__ edge_user,
        const int* __restrict__ rating,
        int* __restrict__ curI, int* __restrict__ curU,
        unsigned* __restrict__ staged1, unsigned* __restrict__ staged2,
        int E, int nTiles, int NU, int NI) {
    const bool dirU = blockIdx.x >= nTiles;
    const int* dst = dirU ? edge_user : edge_item;
    const int* src = dirU ? edge_item : edge_user;
    const int shift = dirU ? 9 : 8;
    const int Ns = dirU ? NI : NU;
    int* coarseCur = dirU ? curU : curI;
    unsigned* staged = dirU ? staged2 : staged1;
    const int tile = (dirU ? blockIdx.x - nTiles : blockIdx.x) * 2048;

    __shared__ unsigned srt[2048];
    __shared__ int sft[2048];
    __shared__ int hist[256], pfx[256], shm[256];
    const int tid = threadIdx.x;
    int cnt = E - tile; if (cnt > 2048) cnt = 2048;
    hist[tid] = 0;
    __syncthreads();
    unsigned rec[8]; int bk[8];
    #pragma unroll
    for (int k = 0; k < 8; ++k) {
        int i = tile + k * 256 + tid;
        bk[k] = -1;
        if (i < E) {
            int d = dst[i], s = src[i], r = rating[i];
            bk[k] = d >> shift;
            rec[k] = (unsigned)(s + r * Ns) | ((unsigned)(d & ((1 << shift) - 1)) << 20);
            atomicAdd(&hist[bk[k]], 1);
        }
    }
    __syncthreads();
    pfx[tid] = hist[tid];
    __syncthreads();
    for (int dd = 1; dd < 256; dd <<= 1) {
        int a = (tid >= dd) ? pfx[tid - dd] : 0;
        __syncthreads();
        pfx[tid] += a;
        __syncthreads();
    }
    int h = hist[tid];
    int excl = pfx[tid] - h;
    int gb = 0;
    if (h > 0) gb = atomicAdd(&coarseCur[tid], h);
    shm[tid] = gb - excl;
    __syncthreads();
    hist[tid] = excl;          // reuse as local cursor
    __syncthreads();
    #pragma unroll
    for (int k = 0; k < 8; ++k) {
        if (bk[k] >= 0) {
            int p = atomicAdd(&hist[bk[k]], 1);
            srt[p] = rec[k];
            sft[p] = shm[bk[k]];
        }
    }
    __syncthreads();
    for (int i = tid; i < cnt; i += 256)
        staged[sft[i] + i] = srt[i];
}

// Pass B, both directions: one block per coarse bucket.
__global__ __launch_bounds__(256) void multisplit_B2(
        unsigned* __restrict__ staged1, unsigned* __restrict__ staged2,
        const int* __restrict__ coarseOffI, const int* __restrict__ coarseOffU,
        int* __restrict__ offI, int* __restrict__ offU,
        int NBI, int NU, int NI, int E) {
    const bool dirU = (int)blockIdx.x >= NBI;
    unsigned* staged = dirU ? staged2 : staged1;
    const int* coarseOff = dirU ? coarseOffU : coarseOffI;
    int* off = dirU ? offU : offI;
    const int N = dirU ? NU : NI;
    const int shift = dirU ? 9 : 8;
    const int b = dirU ? blockIdx.x - NBI : blockIdx.x;
    const int nb = dirU ? (N + (1 << 9) - 1) >> 9 : NBI;

    __shared__ unsigned rec[16384];
    __shared__ int hist[512], pfx[512];
    const int tid = threadIdx.x;
    const int range = 1 << shift;
    int cbase = coarseOff[b];
    int cnt = coarseOff[b + 1] - cbase;
    if (cnt > 16384) cnt = 16384;   // safety guard (never expected)
    hist[tid] = 0; hist[tid + 256] = 0;
    __syncthreads();
    for (int i = tid; i < cnt; i += 256) {
        unsigned x = staged[cbase + i];
        rec[i] = x;
        atomicAdd(&hist[x >> 20], 1);
    }
    __syncthreads();
    pfx[tid] = hist[tid]; pfx[tid + 256] = hist[tid + 256];
    __syncthreads();
    for (int dd = 1; dd < 256; dd <<= 1) {
        int a = (tid >= dd) ? pfx[tid - dd] : 0;
        int c = (tid >= dd) ? pfx[tid + 256 - dd] : 0;
        __syncthreads();
        pfx[tid] += a; pfx[tid + 256] += c;
        __syncthreads();
    }
    int tot0 = pfx[255];
    __syncthreads();
    pfx[tid + 256] += tot0;
    __syncthreads();
    int e0 = pfx[tid] - hist[tid];
    int e1 = pfx[tid + 256] - hist[tid + 256];
    __syncthreads();
    hist[tid] = e0; hist[tid + 256] = e1;   // cursors
    int dbase = b << shift;
    if (dbase + tid < N) off[dbase + tid] = cbase + e0;
    if (range > 256 && dbase + tid + 256 < N) off[dbase + tid + 256] = cbase + e1;
    if (b == nb - 1 && tid == 0) off[N] = E;
    __syncthreads();
    for (int i = tid; i < cnt; i += 256) {
        unsigned x = rec[i];
        int p = atomicAdd(&hist[x >> 20], 1);
        staged[cbase + p] = x;
    }
}

// Per-source-node relation transform, both directions in one launch:
// y[r][s] = Wr[r] @ h[s], bf16, natural dim order.
__global__ __launch_bounds__(256) void pretransform2(
        const unsigned short* __restrict__ hu, const unsigned short* __restrict__ hi,
        const short* __restrict__ pWrW, const short* __restrict__ pWrWB,
        unsigned short* __restrict__ y1, unsigned short* __restrict__ y2,
        int NU, int NI, int wavesU) {
    const int lane = threadIdx.x & 63;
    const int m = lane & 15, q = lane >> 4;
    int wave = (blockIdx.x * blockDim.x + threadIdx.x) >> 6;
    const bool dirI = wave >= wavesU;
    const unsigned short* h = dirI ? hi : hu;
    const short* pWr = dirI ? pWrWB : pWrW;
    unsigned short* y = dirI ? y2 : y1;
    const int Ns = dirI ? NI : NU;
    if (dirI) wave -= wavesU;
    const int n0 = wave * 16;
    if (n0 >= Ns) return;
    int nrow = n0 + m; if (nrow > Ns - 1) nrow = Ns - 1;

    bf16x8 bB[2];
    {
        const unsigned short* ph = h + (size_t)nrow * D + q * 8;
        bB[0] = *(const bf16x8*)(ph);
        bB[1] = *(const bf16x8*)(ph + 32);
    }
    const int srcA = ((q & 1) << 5) + m;
    const int srcB = srcA + 16;
    const bool hiq = (q >> 1) != 0;

    #pragma unroll
    for (int r = 0; r < NRAT; ++r) {
        f32x4 acc[4] = {};
        #pragma unroll
        for (int it = 0; it < 4; ++it)
            #pragma unroll
            for (int kt = 0; kt < 2; ++kt) {
                bf16x8 a = *(const bf16x8*)(pWr + (((r * 4 + it) * 2 + kt) << 9) + (lane << 3));
                acc[it] = __builtin_amdgcn_mfma_f32_16x16x32_bf16(a, bB[kt], acc[it], 0, 0, 0);
            }
        uint32_t u0[4], u1[4];
        #pragma unroll
        for (int it = 0; it < 4; ++it) {
            u0[it] = pk2(acc[it][0], acc[it][1]);
            u1[it] = pk2(acc[it][2], acc[it][3]);
        }
        #pragma unroll
        for (int w = 0; w < 2; ++w) {
            uint32_t aa0 = (uint32_t)__shfl((int)u0[2*w],   srcA), bb0 = (uint32_t)__shfl((int)u0[2*w+1], srcA);
            uint32_t aa1 = (uint32_t)__shfl((int)u1[2*w],   srcA), bb1 = (uint32_t)__shfl((int)u1[2*w+1], srcA);
            uint32_t aa2 = (uint32_t)__shfl((int)u0[2*w],   srcB), bb2 = (uint32_t)__shfl((int)u0[2*w+1], srcB);
            uint32_t aa3 = (uint32_t)__shfl((int)u1[2*w],   srcB), bb3 = (uint32_t)__shfl((int)u1[2*w+1], srcB);
            FragU f;
            f.u[0] = hiq ? bb0 : aa0;
            f.u[1] = hiq ? bb1 : aa1;
            f.u[2] = hiq ? bb2 : aa2;
            f.u[3] = hiq ? bb3 : aa3;
            *(bf16x8*)(y + ((size_t)r * Ns + nrow) * D + w * 32 + q * 8) = f.v;
        }
    }
}

// One wave per dst node, both directions: rating-oblivious gather-mean of
// pre-transformed y rows. 32-bit offset math: off = (rec20 << 6) | lane.
__global__ __launch_bounds__(256) void gather_both(
        const int* __restrict__ offI, const int* __restrict__ offU,
        const unsigned* __restrict__ staged1, const unsigned* __restrict__ staged2,
        const unsigned short* __restrict__ y1, const unsigned short* __restrict__ y2,
        unsigned short* __restrict__ hn1, unsigned short* __restrict__ hn2,
        int NI, int NU) {
    const unsigned lane = threadIdx.x & 63;
    int g = (blockIdx.x * blockDim.x + threadIdx.x) >> 6;
    const bool dirU = g >= NI;
    int n = dirU ? g - NI : g;
    if (dirU && n >= NU) return;
    const int* off = dirU ? offU : offI;
    const unsigned* packed = dirU ? staged2 : staged1;
    const unsigned short* y = dirU ? y2 : y1;
    unsigned short* hn = dirU ? hn2 : hn1;

    int b = off[n], e = off[n + 1];
    float a0 = 0.f, a1 = 0.f, a2 = 0.f, a3 = 0.f;

#define YLD(mm) __uint_as_float(((unsigned)y[((((mm) << 6) & 0x3FFFFC0u) | lane)]) << 16)

    for (int base = b; base < e; base += 64) {
        int idx = base + (int)lane; if (idx > e - 1) idx = e - 1;
        unsigned meta = packed[idx];
        int cnt = e - base; if (cnt > 64) cnt = 64;
        int j = 0;
        for (; j + 4 <= cnt; j += 4) {
            unsigned m0 = (unsigned)__builtin_amdgcn_readlane((int)meta, j);
            unsigned m1 = (unsigned)__builtin_amdgcn_readlane((int)meta, j + 1);
            unsigned m2 = (unsigned)__builtin_amdgcn_readlane((int)meta, j + 2);
            unsigned m3 = (unsigned)__builtin_amdgcn_readlane((int)meta, j + 3);
            a0 += YLD(m0); a1 += YLD(m1); a2 += YLD(m2); a3 += YLD(m3);
        }
        for (; j < cnt; ++j) {
            unsigned mm = (unsigned)__builtin_amdgcn_readlane((int)meta, j);
            a0 += YLD(mm);
        }
    }
#undef YLD
    float inv = 1.0f / fmaxf((float)(e - b), 1.0f);
    hn[(size_t)n * D + lane] = (unsigned short)f2bf(((a0 + a1) + (a2 + a3)) * inv);
}

// Per-16-node-tile MFMA transform, both directions:
//   GEMM2 (transposed): h2^T = relu(Wlin @ [hd|hn]^T + blin)
//   GEMM3 (normal):     out  = h2 @ W2^T + b2
__global__ __launch_bounds__(256) void transform_both(
        const unsigned short* __restrict__ hn1, const unsigned short* __restrict__ hn2,
        const unsigned short* __restrict__ hi, const unsigned short* __restrict__ hu,
        const short* __restrict__ pWw, const short* __restrict__ pWwb,
        const float* __restrict__ bw, const float* __restrict__ bwb,
        const short* __restrict__ pVf, const short* __restrict__ pWf,
        const float* __restrict__ bv, const float* __restrict__ bf,
        float* __restrict__ item_out, float* __restrict__ user_out,
        int NI, int NU, int tilesI) {
    const int lane = threadIdx.x & 63;
    const int m = lane & 15, q = lane >> 4;
    int wave = (blockIdx.x * blockDim.x + threadIdx.x) >> 6;
    const bool dirU = wave >= tilesI;
    if (dirU) wave -= tilesI;
    const unsigned short* hn = dirU ? hn2 : hn1;
    const unsigned short* hd = dirU ? hu : hi;
    const short* pWlin = dirU ? pWwb : pWw;
    const float* blin  = dirU ? bwb : bw;
    const short* pW2   = dirU ? pWf : pVf;
    const float* b2    = dirU ? bf : bv;
    float* out = dirU ? user_out : item_out;
    const int N = dirU ? NU : NI;
    const int n0 = wave * 16;
    if (n0 >= N) return;
    int nrow = n0 + m; if (nrow > N - 1) nrow = N - 1;

    bf16x8 bH[2], bHN[2];
    {
        const unsigned short* ph = hd + (size_t)nrow * D + q * 8;
        bH[0] = *(const bf16x8*)(ph);
        bH[1] = *(const bf16x8*)(ph + 32);
        const unsigned short* pn = hn + (size_t)nrow * D + q * 8;
        bHN[0] = *(const bf16x8*)(pn);
        bHN[1] = *(const bf16x8*)(pn + 32);
    }

    f32x4 acc2[4] = {};
    #pragma unroll
    for (int it = 0; it < 4; ++it)
        #pragma unroll
        for (int kt = 0; kt < 4; ++kt) {
            bf16x8 a = *(const bf16x8*)(pWlin + (((it * 4) + kt) << 9) + (lane << 3));
            bf16x8 b = (kt < 2) ? bH[kt] : bHN[kt - 2];
            acc2[it] = __builtin_amdgcn_mfma_f32_16x16x32_bf16(a, b, acc2[it], 0, 0, 0);
        }

    const int srcA = ((q & 1) << 5) + m;
    const int srcB = srcA + 16;
    const bool hiq = (q >> 1) != 0;
    uint32_t u0[4], u1[4];
    float vbl = blin[lane];
    #pragma unroll
    for (int it = 0; it < 4; ++it) {
        float h0 = fmaxf(acc2[it][0] + __shfl(vbl, it * 16 + q * 4 + 0), 0.f);
        float h1 = fmaxf(acc2[it][1] + __shfl(vbl, it * 16 + q * 4 + 1), 0.f);
        float h2 = fmaxf(acc2[it][2] + __shfl(vbl, it * 16 + q * 4 + 2), 0.f);
        float h3 = fmaxf(acc2[it][3] + __shfl(vbl, it * 16 + q * 4 + 3), 0.f);
        u0[it] = pk2(h0, h1);
        u1[it] = pk2(h2, h3);
    }
    bf16x8 bA3[2];
    #pragma unroll
    for (int w = 0; w < 2; ++w) {
        uint32_t aa0 = (uint32_t)__shfl((int)u0[2*w],   srcA), bb0 = (uint32_t)__shfl((int)u0[2*w+1], srcA);
        uint32_t aa1 = (uint32_t)__shfl((int)u1[2*w],   srcA), bb1 = (uint32_t)__shfl((int)u1[2*w+1], srcA);
        uint32_t aa2 = (uint32_t)__shfl((int)u0[2*w],   srcB), bb2 = (uint32_t)__shfl((int)u0[2*w+1], srcB);
        uint32_t aa3 = (uint32_t)__shfl((int)u1[2*w],   srcB), bb3 = (uint32_t)__shfl((int)u1[2*w+1], srcB);
        FragU f;
        f.u[0] = hiq ? bb0 : aa0;
        f.u[1] = hiq ? bb1 : aa1;
        f.u[2] = hiq ? bb2 : aa2;
        f.u[3] = hiq ? bb3 : aa3;
        bA3[w] = f.v;
    }

    f32x4 acc3[4] = {};
    #pragma unroll
    for (int ct = 0; ct < 4; ++ct)
        #pragma unroll
        for (int kt = 0; kt < 2; ++kt) {
            bf16x8 b = *(const bf16x8*)(pW2 + (((ct * 2) + kt) << 9) + (lane << 3));
            acc3[ct] = __builtin_amdgcn_mfma_f32_16x16x32_bf16(bA3[kt], b, acc3[ct], 0, 0, 0);
        }
    #pragma unroll
    for (int ct = 0; ct < 4; ++ct) {
        float bb = b2[ct * 16 + m];
        #pragma unroll
        for (int rg = 0; rg < 4; ++rg) {
            int n = n0 + q * 4 + rg;
            if (n < N) out[(size_t)n * D + ct * 16 + m] = acc3[ct][rg] + bb;
        }
    }
}

extern "C" void kernel_launch(void* const* d_in, const int* in_sizes, int n_in,
                              void* d_out, int out_size, void* d_ws, size_t ws_size,
                              hipStream_t stream) {
    const int*   user_ids   = (const int*)  d_in[0];
    const int*   item_ids   = (const int*)  d_in[1];
    const int*   gender     = (const int*)  d_in[2];
    const int*   genres     = (const int*)  d_in[3];
    const int*   edge_user  = (const int*)  d_in[4];
    const int*   edge_item  = (const int*)  d_in[5];
    const int*   rating     = (const int*)  d_in[6];
    const float* user_emb   = (const float*)d_in[7];
    const float* item_emb   = (const float*)d_in[8];
    const float* gender_emb = (const float*)d_in[9];
    const float* genre_emb  = (const float*)d_in[10];
    const float* Wr_watched   = (const float*)d_in[11];
    const float* Wr_watchedby = (const float*)d_in[12];
    const float* Ww  = (const float*)d_in[13];
    const float* bw  = (const float*)d_in[14];
    const float* Wwb = (const float*)d_in[15];
    const float* bwb = (const float*)d_in[16];
    const float* Wf  = (const float*)d_in[17];
    const float* bf  = (const float*)d_in[18];
    const float* Vf  = (const float*)d_in[19];
    const float* bv  = (const float*)d_in[20];

    const int NU = in_sizes[0];
    const int NI = in_sizes[1];
    const int E  = in_sizes[4];
    const int NBI = (NI + 255) >> 8;   // coarse buckets (shift 8)
    const int NBU = (NU + 511) >> 9;   // coarse buckets (shift 9)

    float* out_f    = (float*)d_out;
    float* user_out = out_f;                       // [NU,64]
    float* item_out = out_f + (size_t)NU * D;      // [NI,64]

    // ws layout (bf16 first): hu, hi, hn1, hn2, y1, y2, packs, ints, staged x2
    unsigned short* hu  = (unsigned short*)d_ws;
    unsigned short* hi  = hu  + (size_t)NU * D;
    unsigned short* hn1 = hi  + (size_t)NI * D;            // items' agg
    unsigned short* hn2 = hn1 + (size_t)NI * D;            // users' agg
    unsigned short* y1  = hn2 + (size_t)NU * D;            // [6][NU][64]
    unsigned short* y2  = y1  + (size_t)NRAT * NU * D;     // [6][NI][64]
    size_t bfElems = (size_t)(2 * NU + 2 * NI) * D + (size_t)NRAT * (NU + NI) * D;
    size_t byteOff = (bfElems * 2 + 15) & ~(size_t)15;
    short* pWrW  = (short*)((char*)d_ws + byteOff);
    short* pWrWB = pWrW  + 24576;
    short* pWw   = pWrWB + 24576;
    short* pWwb  = pWw   + 8192;
    short* pVf   = pWwb  + 8192;
    short* pWf   = pVf   + 4096;
    int* coarseCntI = (int*)(pWf + 4096);   // 256, start of zeroRegion
    int* coarseCntU = coarseCntI + 256;     // 256
    int* done       = coarseCntU + 256;     // 1, end of zeroRegion (513 ints)
    int* coarseOffI = done + 1;             // 257
    int* coarseOffU = coarseOffI + 257;     // 257
    int* coarseCurI = coarseOffU + 257;     // 256
    int* coarseCurU = coarseCurI + 256;     // 256
    int* offI   = coarseCurU + 256;         // NI+1
    int* offU   = offI + NI + 1;            // NU+1
    unsigned* staged1 = (unsigned*)(offU + NU + 1);  // E
    unsigned* staged2 = staged1 + E;                 // E

    // 1. setup: node features + weight packing + counter zeroing (1 dispatch)
    int totalh = (NU + NI) * 16;
    build_setup<<<(totalh + 255) / 256, 256, 0, stream>>>(
        user_ids, item_ids, gender, genres,
        user_emb, item_emb, gender_emb, genre_emb, hu, hi, coarseCntI,
        Wr_watched, Wr_watchedby, Ww, Wwb, Vf, Wf,
        pWrW, pWrWB, pWw, pWwb, pVf, pWf, NU, NI);

    // 2. histogram + coarse scan (last-block pattern, 1 dispatch)
    hist_scan<<<512, 256, 0, stream>>>(edge_item, edge_user, coarseCntI, coarseCntU,
                                       done, coarseOffI, coarseOffU,
                                       coarseCurI, coarseCurU, NBI, NBU, E);

    // 3. sort both directions
    const int nTilesA = (E + 2047) / 2048;
    multisplit_A2<<<2 * nTilesA, 256, 0, stream>>>(edge_item, edge_user, rating,
                                                   coarseCurI, coarseCurU,
                                                   staged1, staged2, E, nTilesA, NU, NI);
    multisplit_B2<<<NBI + NBU, 256, 0, stream>>>(staged1, staged2, coarseOffI, coarseOffU,
                                                 offI, offU, NBI, NU, NI, E);

    // 4. pretransform both, gather both, transform both
    {
        int wavesU = (NU + 15) / 16, wavesI = (NI + 15) / 16;
        int blocks = (wavesU + wavesI + 3) / 4;
        pretransform2<<<blocks, 256, 0, stream>>>(hu, hi, pWrW, pWrWB, y1, y2, NU, NI, wavesU);
    }
    gather_both<<<(NI + NU + 3) / 4, 256, 0, stream>>>(offI, offU, staged1, staged2,
                                                       y1, y2, hn1, hn2, NI, NU);
    {
        int tilesI = (NI + 15) / 16, tilesU = (NU + 15) / 16;
        int blocks = (tilesI + tilesU + 3) / 4;
        transform_both<<<blocks, 256, 0, stream>>>(hn1, hn2, hi, hu, pWw, pWwb, bw, bwb,
                                                   pVf, pWf, bv, bf, item_out, user_out,
                                                   NI, NU, tilesI);
    }
}

// Round 12
// 236.609 us; speedup vs baseline: 1.1282x; 1.1282x over previous
//
#include <hip/hip_runtime.h>
#include <hip/hip_bf16.h>

#define D 64
#define NRAT 6

typedef float f32x4 __attribute__((ext_vector_type(4)));
typedef short bf16x8 __attribute__((ext_vector_type(8)));

union FragU { uint32_t u[4]; bf16x8 v; };

__device__ __forceinline__ short f2bf(float f) {
    __hip_bfloat16 h = __float2bfloat16(f);
    union { __hip_bfloat16 h; short s; } c; c.h = h; return c.s;
}
__device__ __forceinline__ uint32_t pk2(float a, float b) {
    union { short s[2]; uint32_t u; } c; c.s[0] = f2bf(a); c.s[1] = f2bf(b); return c.u;
}

// Fused setup: (a) t<512 zero coarse counters; (b) node features hu/hi in
// bf16; (c) threads [1024,1024+73728) pack all weights to MFMA frag order.
__global__ void build_setup(const int* __restrict__ uid, const int* __restrict__ iid,
                            const int* __restrict__ gender, const int* __restrict__ genres,
                            const float* __restrict__ user_emb, const float* __restrict__ item_emb,
                            const float* __restrict__ gender_emb, const float* __restrict__ genre_emb,
                            unsigned short* __restrict__ hu, unsigned short* __restrict__ hi,
                            int* __restrict__ zeroRegion,
                            const float* __restrict__ Wr_w, const float* __restrict__ Wr_wb,
                            const float* __restrict__ Ww, const float* __restrict__ Wwb,
                            const float* __restrict__ Vf, const float* __restrict__ Wf,
                            short* __restrict__ pWrW, short* __restrict__ pWrWB,
                            short* __restrict__ pWw, short* __restrict__ pWwb,
                            short* __restrict__ pVf, short* __restrict__ pWf,
                            int NU, int NI) {
    int t = blockIdx.x * blockDim.x + threadIdx.x;
    if (t < 512) zeroRegion[t] = 0;      // cntI(256) + cntU(256)

    int tp = t - 1024;
    if (tp >= 0 && tp < 73728) {
        const float* src; short* dst; int K; int idx;
        if      (tp < 24576) { src = Wr_w;  dst = pWrW;  K = 64;  idx = tp; }
        else if (tp < 49152) { src = Wr_wb; dst = pWrWB; K = 64;  idx = tp - 24576; }
        else if (tp < 57344) { src = Ww;    dst = pWw;   K = 128; idx = tp - 49152; }
        else if (tp < 65536) { src = Wwb;   dst = pWwb;  K = 128; idx = tp - 57344; }
        else if (tp < 69632) { src = Vf;    dst = pVf;   K = 64;  idx = tp - 65536; }
        else                 { src = Wf;    dst = pWf;   K = 64;  idx = tp - 69632; }
        int per  = 64 * K;
        int sub  = idx / per;
        int li   = idx % per;
        int e    = li & 7;
        int lane = (li >> 3) & 63;
        int frag = li >> 9;
        int nkt  = K >> 5;
        int t16  = frag / nkt, tk = frag % nkt;
        int row  = t16 * 16 + (lane & 15);
        int col  = tk * 32 + (lane >> 4) * 8 + e;
        dst[idx] = f2bf(src[((size_t)(sub * 64 + row)) * K + col]);
    }

    int total = (NU + NI) * 16;          // one float4 (4 dims) per thread
    if (t >= total) return;
    int row = t >> 4, c = t & 15;
    uint2 o;
    if (row < NU) {
        int u = uid[row], g = gender[row];
        float4 a = ((const float4*)user_emb)[(size_t)u * 16 + c];
        float4 b = ((const float4*)gender_emb)[(size_t)g * 16 + c];
        o.x = pk2(a.x + b.x, a.y + b.y); o.y = pk2(a.z + b.z, a.w + b.w);
        ((uint2*)hu)[(size_t)row * 16 + c] = o;
    } else {
        int r2 = row - NU;
        int it = iid[r2], ge = genres[r2];
        float4 a = ((const float4*)item_emb)[(size_t)it * 16 + c];
        float4 b = ((const float4*)genre_emb)[(size_t)ge * 16 + c];
        o.x = pk2(a.x + b.x, a.y + b.y); o.y = pk2(a.z + b.z, a.w + b.w);
        ((uint2*)hi)[(size_t)r2 * 16 + c] = o;
    }
}

// One pass over both edge arrays: LDS hists for items (>>8) and users (>>9).
__global__ __launch_bounds__(256) void hist_both(const int* __restrict__ edge_item,
                                                 const int* __restrict__ edge_user,
                                                 int* __restrict__ cntI, int* __restrict__ cntU,
                                                 int E) {
    __shared__ int hI[256], hU[256];
    hI[threadIdx.x] = 0; hU[threadIdx.x] = 0;
    __syncthreads();
    for (int i = blockIdx.x * blockDim.x + threadIdx.x; i < E; i += gridDim.x * blockDim.x) {
        atomicAdd(&hI[edge_item[i] >> 8], 1);
        atomicAdd(&hU[edge_user[i] >> 9], 1);
    }
    __syncthreads();
    int vi = hI[threadIdx.x], vu = hU[threadIdx.x];
    if (vi) atomicAdd(&cntI[threadIdx.x], vi);
    if (vu) atomicAdd(&cntU[threadIdx.x], vu);
}

// 2 blocks: block 0 scans items' coarse counts, block 1 users'.
__global__ __launch_bounds__(256) void scan_both(const int* __restrict__ cntI,
                                                 const int* __restrict__ cntU,
                                                 int* __restrict__ offI, int* __restrict__ offU,
                                                 int* __restrict__ curI, int* __restrict__ curU,
                                                 int NBI, int NBU, int E) {
    const int* cnt = blockIdx.x ? cntU : cntI;
    int* coarseOff  = blockIdx.x ? offU : offI;
    int* coarseCur  = blockIdx.x ? curU : curI;
    int NB          = blockIdx.x ? NBU : NBI;
    __shared__ int p[256];
    int tid = threadIdx.x;
    int v = (tid < NB) ? cnt[tid] : 0;
    p[tid] = v; __syncthreads();
    for (int dd = 1; dd < 256; dd <<= 1) {
        int a = (tid >= dd) ? p[tid - dd] : 0;
        __syncthreads();
        p[tid] += a;
        __syncthreads();
    }
    int excl = p[tid] - v;
    if (tid < NB) { coarseOff[tid] = excl; coarseCur[tid] = excl; }
    if (tid == 0) coarseOff[NB] = E;
}

// Pass A, both directions. Record = (r*Ns + src)(20b) | dstLow(<=9b at bit 20).
__global__ __launch_bounds__(256) void multisplit_A2(
        const int* __restrict__ edge_item, const int* __restrict__ edge_user,
        const int* __restrict__ rating,
        int* __restrict__ curI, int* __restrict__ curU,
        unsigned* __restrict__ staged1, unsigned* __restrict__ staged2,
        int E, int nTiles, int NU, int NI) {
    const bool dirU = blockIdx.x >= nTiles;
    const int* dst = dirU ? edge_user : edge_item;
    const int* src = dirU ? edge_item : edge_user;
    const int shift = dirU ? 9 : 8;
    const int Ns = dirU ? NI : NU;
    int* coarseCur = dirU ? curU : curI;
    unsigned* staged = dirU ? staged2 : staged1;
    const int tile = (dirU ? blockIdx.x - nTiles : blockIdx.x) * 2048;

    __shared__ unsigned srt[2048];
    __shared__ int sft[2048];
    __shared__ int hist[256], pfx[256], shm[256];
    const int tid = threadIdx.x;
    int cnt = E - tile; if (cnt > 2048) cnt = 2048;
    hist[tid] = 0;
    __syncthreads();
    unsigned rec[8]; int bk[8];
    #pragma unroll
    for (int k = 0; k < 8; ++k) {
        int i = tile + k * 256 + tid;
        bk[k] = -1;
        if (i < E) {
            int d = dst[i], s = src[i], r = rating[i];
            bk[k] = d >> shift;
            rec[k] = (unsigned)(s + r * Ns) | ((unsigned)(d & ((1 << shift) - 1)) << 20);
            atomicAdd(&hist[bk[k]], 1);
        }
    }
    __syncthreads();
    pfx[tid] = hist[tid];
    __syncthreads();
    for (int dd = 1; dd < 256; dd <<= 1) {
        int a = (tid >= dd) ? pfx[tid - dd] : 0;
        __syncthreads();
        pfx[tid] += a;
        __syncthreads();
    }
    int h = hist[tid];
    int excl = pfx[tid] - h;
    int gb = 0;
    if (h > 0) gb = atomicAdd(&coarseCur[tid], h);
    shm[tid] = gb - excl;
    __syncthreads();
    hist[tid] = excl;          // reuse as local cursor
    __syncthreads();
    #pragma unroll
    for (int k = 0; k < 8; ++k) {
        if (bk[k] >= 0) {
            int p = atomicAdd(&hist[bk[k]], 1);
            srt[p] = rec[k];
            sft[p] = shm[bk[k]];
        }
    }
    __syncthreads();
    for (int i = tid; i < cnt; i += 256)
        staged[sft[i] + i] = srt[i];
}

// Pass B, both directions: one block per coarse bucket.
__global__ __launch_bounds__(256) void multisplit_B2(
        unsigned* __restrict__ staged1, unsigned* __restrict__ staged2,
        const int* __restrict__ coarseOffI, const int* __restrict__ coarseOffU,
        int* __restrict__ offI, int* __restrict__ offU,
        int NBI, int NU, int NI, int E) {
    const bool dirU = (int)blockIdx.x >= NBI;
    unsigned* staged = dirU ? staged2 : staged1;
    const int* coarseOff = dirU ? coarseOffU : coarseOffI;
    int* off = dirU ? offU : offI;
    const int N = dirU ? NU : NI;
    const int shift = dirU ? 9 : 8;
    const int b = dirU ? blockIdx.x - NBI : blockIdx.x;
    const int nb = dirU ? (N + (1 << 9) - 1) >> 9 : NBI;

    __shared__ unsigned rec[16384];
    __shared__ int hist[512], pfx[512];
    const int tid = threadIdx.x;
    const int range = 1 << shift;
    int cbase = coarseOff[b];
    int cnt = coarseOff[b + 1] - cbase;
    if (cnt > 16384) cnt = 16384;   // safety guard (never expected)
    hist[tid] = 0; hist[tid + 256] = 0;
    __syncthreads();
    for (int i = tid; i < cnt; i += 256) {
        unsigned x = staged[cbase + i];
        rec[i] = x;
        atomicAdd(&hist[x >> 20], 1);
    }
    __syncthreads();
    pfx[tid] = hist[tid]; pfx[tid + 256] = hist[tid + 256];
    __syncthreads();
    for (int dd = 1; dd < 256; dd <<= 1) {
        int a = (tid >= dd) ? pfx[tid - dd] : 0;
        int c = (tid >= dd) ? pfx[tid + 256 - dd] : 0;
        __syncthreads();
        pfx[tid] += a; pfx[tid + 256] += c;
        __syncthreads();
    }
    int tot0 = pfx[255];
    __syncthreads();
    pfx[tid + 256] += tot0;
    __syncthreads();
    int e0 = pfx[tid] - hist[tid];
    int e1 = pfx[tid + 256] - hist[tid + 256];
    __syncthreads();
    hist[tid] = e0; hist[tid + 256] = e1;   // cursors
    int dbase = b << shift;
    if (dbase + tid < N) off[dbase + tid] = cbase + e0;
    if (range > 256 && dbase + tid + 256 < N) off[dbase + tid + 256] = cbase + e1;
    if (b == nb - 1 && tid == 0) off[N] = E;
    __syncthreads();
    for (int i = tid; i < cnt; i += 256) {
        unsigned x = rec[i];
        int p = atomicAdd(&hist[x >> 20], 1);
        staged[cbase + p] = x;
    }
}

// Per-source-node relation transform, both directions in one launch:
// y[r][s] = Wr[r] @ h[s], bf16, natural dim order.
__global__ __launch_bounds__(256) void pretransform2(
        const unsigned short* __restrict__ hu, const unsigned short* __restrict__ hi,
        const short* __restrict__ pWrW, const short* __restrict__ pWrWB,
        unsigned short* __restrict__ y1, unsigned short* __restrict__ y2,
        int NU, int NI, int wavesU) {
    const int lane = threadIdx.x & 63;
    const int m = lane & 15, q = lane >> 4;
    int wave = (blockIdx.x * blockDim.x + threadIdx.x) >> 6;
    const bool dirI = wave >= wavesU;
    const unsigned short* h = dirI ? hi : hu;
    const short* pWr = dirI ? pWrWB : pWrW;
    unsigned short* y = dirI ? y2 : y1;
    const int Ns = dirI ? NI : NU;
    if (dirI) wave -= wavesU;
    const int n0 = wave * 16;
    if (n0 >= Ns) return;
    int nrow = n0 + m; if (nrow > Ns - 1) nrow = Ns - 1;

    bf16x8 bB[2];
    {
        const unsigned short* ph = h + (size_t)nrow * D + q * 8;
        bB[0] = *(const bf16x8*)(ph);
        bB[1] = *(const bf16x8*)(ph + 32);
    }
    const int srcA = ((q & 1) << 5) + m;
    const int srcB = srcA + 16;
    const bool hiq = (q >> 1) != 0;

    #pragma unroll
    for (int r = 0; r < NRAT; ++r) {
        f32x4 acc[4] = {};
        #pragma unroll
        for (int it = 0; it < 4; ++it)
            #pragma unroll
            for (int kt = 0; kt < 2; ++kt) {
                bf16x8 a = *(const bf16x8*)(pWr + (((r * 4 + it) * 2 + kt) << 9) + (lane << 3));
                acc[it] = __builtin_amdgcn_mfma_f32_16x16x32_bf16(a, bB[kt], acc[it], 0, 0, 0);
            }
        uint32_t u0[4], u1[4];
        #pragma unroll
        for (int it = 0; it < 4; ++it) {
            u0[it] = pk2(acc[it][0], acc[it][1]);
            u1[it] = pk2(acc[it][2], acc[it][3]);
        }
        #pragma unroll
        for (int w = 0; w < 2; ++w) {
            uint32_t aa0 = (uint32_t)__shfl((int)u0[2*w],   srcA), bb0 = (uint32_t)__shfl((int)u0[2*w+1], srcA);
            uint32_t aa1 = (uint32_t)__shfl((int)u1[2*w],   srcA), bb1 = (uint32_t)__shfl((int)u1[2*w+1], srcA);
            uint32_t aa2 = (uint32_t)__shfl((int)u0[2*w],   srcB), bb2 = (uint32_t)__shfl((int)u0[2*w+1], srcB);
            uint32_t aa3 = (uint32_t)__shfl((int)u1[2*w],   srcB), bb3 = (uint32_t)__shfl((int)u1[2*w+1], srcB);
            FragU f;
            f.u[0] = hiq ? bb0 : aa0;
            f.u[1] = hiq ? bb1 : aa1;
            f.u[2] = hiq ? bb2 : aa2;
            f.u[3] = hiq ? bb3 : aa3;
            *(bf16x8*)(y + ((size_t)r * Ns + nrow) * D + w * 32 + q * 8) = f.v;
        }
    }
}

// One wave per dst node, both directions. 2 edges per iteration: lanes 0-31
// read edge j's 128B y-row as dwords (2 bf16 dims/lane), lanes 32-63 edge
// j+1's. Cross-half combine at the end; half-wave dword store of hn.
__global__ __launch_bounds__(256) void gather_both(
        const int* __restrict__ offI, const int* __restrict__ offU,
        const unsigned* __restrict__ staged1, const unsigned* __restrict__ staged2,
        const unsigned* __restrict__ y1, const unsigned* __restrict__ y2,
        unsigned* __restrict__ hn1, unsigned* __restrict__ hn2,
        int NI, int NU) {
    const int lane = threadIdx.x & 63;
    const int half = lane >> 5;          // 0 or 1
    const int l5   = lane & 31;
    int g = (blockIdx.x * blockDim.x + threadIdx.x) >> 6;
    const bool dirU = g >= NI;
    int n = dirU ? g - NI : g;
    if (dirU && n >= NU) return;
    const int* off = dirU ? offU : offI;
    const unsigned* packed = dirU ? staged2 : staged1;
    const unsigned* y = dirU ? y2 : y1;       // dword view: [rows][32]
    unsigned* hn = dirU ? hn2 : hn1;          // dword view: [N][32]

    int b = off[n], e = off[n + 1];
    float a0 = 0.f, a1 = 0.f;                 // dims 2*l5, 2*l5+1 (this half)

#define YPAIR(mm) y[(((mm) << 5) & 0x1FFFFE0u) | (unsigned)l5]
#define ACC2(dd) { a0 += __uint_as_float((dd) << 16); \
                   a1 += __uint_as_float((dd) & 0xFFFF0000u); }

    for (int base = b; base < e; base += 64) {
        int idx = base + lane; if (idx > e - 1) idx = e - 1;
        unsigned meta = packed[idx];
        int cnt = e - base; if (cnt > 64) cnt = 64;
        int j = 0;
        for (; j + 4 <= cnt; j += 4) {
            unsigned mA = (unsigned)__shfl((int)meta, j + half);
            unsigned mB = (unsigned)__shfl((int)meta, j + 2 + half);
            unsigned dA = YPAIR(mA);
            unsigned dB = YPAIR(mB);
            ACC2(dA); ACC2(dB);
        }
        if (j + 2 <= cnt) {
            unsigned mA = (unsigned)__shfl((int)meta, j + half);
            unsigned dA = YPAIR(mA);
            ACC2(dA);
            j += 2;
        }
        if (j < cnt) {      // odd tail: half 0 processes, half 1 adds nothing
            unsigned mm = (unsigned)__builtin_amdgcn_readlane((int)meta, j);
            if (half == 0) { unsigned dd = YPAIR(mm); ACC2(dd); }
        }
    }
#undef YPAIR
#undef ACC2

    // combine halves (lane ^ 32 holds the other half's partial for same dims)
    float o0 = __shfl(a0, lane ^ 32);
    float o1 = __shfl(a1, lane ^ 32);
    float inv = 1.0f / fmaxf((float)(e - b), 1.0f);
    float s0 = (a0 + o0) * inv;
    float s1 = (a1 + o1) * inv;
    if (lane < 32) hn[(size_t)n * 32 + l5] = pk2(s0, s1);
}

// Per-16-node-tile MFMA transform, both directions:
//   GEMM2 (transposed): h2^T = relu(Wlin @ [hd|hn]^T + blin)
//   GEMM3 (normal):     out  = h2 @ W2^T + b2
__global__ __launch_bounds__(256) void transform_both(
        const unsigned short* __restrict__ hn1, const unsigned short* __restrict__ hn2,
        const unsigned short* __restrict__ hi, const unsigned short* __restrict__ hu,
        const short* __restrict__ pWw, const short* __restrict__ pWwb,
        const float* __restrict__ bw, const float* __restrict__ bwb,
        const short* __restrict__ pVf, const short* __restrict__ pWf,
        const float* __restrict__ bv, const float* __restrict__ bf,
        float* __restrict__ item_out, float* __restrict__ user_out,
        int NI, int NU, int tilesI) {
    const int lane = threadIdx.x & 63;
    const int m = lane & 15, q = lane >> 4;
    int wave = (blockIdx.x * blockDim.x + threadIdx.x) >> 6;
    const bool dirU = wave >= tilesI;
    if (dirU) wave -= tilesI;
    const unsigned short* hn = dirU ? hn2 : hn1;
    const unsigned short* hd = dirU ? hu : hi;
    const short* pWlin = dirU ? pWwb : pWw;
    const float* blin  = dirU ? bwb : bw;
    const short* pW2   = dirU ? pWf : pVf;
    const float* b2    = dirU ? bf : bv;
    float* out = dirU ? user_out : item_out;
    const int N = dirU ? NU : NI;
    const int n0 = wave * 16;
    if (n0 >= N) return;
    int nrow = n0 + m; if (nrow > N - 1) nrow = N - 1;

    bf16x8 bH[2], bHN[2];
    {
        const unsigned short* ph = hd + (size_t)nrow * D + q * 8;
        bH[0] = *(const bf16x8*)(ph);
        bH[1] = *(const bf16x8*)(ph + 32);
        const unsigned short* pn = hn + (size_t)nrow * D + q * 8;
        bHN[0] = *(const bf16x8*)(pn);
        bHN[1] = *(const bf16x8*)(pn + 32);
    }

    f32x4 acc2[4] = {};
    #pragma unroll
    for (int it = 0; it < 4; ++it)
        #pragma unroll
        for (int kt = 0; kt < 4; ++kt) {
            bf16x8 a = *(const bf16x8*)(pWlin + (((it * 4) + kt) << 9) + (lane << 3));
            bf16x8 b = (kt < 2) ? bH[kt] : bHN[kt - 2];
            acc2[it] = __builtin_amdgcn_mfma_f32_16x16x32_bf16(a, b, acc2[it], 0, 0, 0);
        }

    const int srcA = ((q & 1) << 5) + m;
    const int srcB = srcA + 16;
    const bool hiq = (q >> 1) != 0;
    uint32_t u0[4], u1[4];
    float vbl = blin[lane];
    #pragma unroll
    for (int it = 0; it < 4; ++it) {
        float h0 = fmaxf(acc2[it][0] + __shfl(vbl, it * 16 + q * 4 + 0), 0.f);
        float h1 = fmaxf(acc2[it][1] + __shfl(vbl, it * 16 + q * 4 + 1), 0.f);
        float h2 = fmaxf(acc2[it][2] + __shfl(vbl, it * 16 + q * 4 + 2), 0.f);
        float h3 = fmaxf(acc2[it][3] + __shfl(vbl, it * 16 + q * 4 + 3), 0.f);
        u0[it] = pk2(h0, h1);
        u1[it] = pk2(h2, h3);
    }
    bf16x8 bA3[2];
    #pragma unroll
    for (int w = 0; w < 2; ++w) {
        uint32_t aa0 = (uint32_t)__shfl((int)u0[2*w],   srcA), bb0 = (uint32_t)__shfl((int)u0[2*w+1], srcA);
        uint32_t aa1 = (uint32_t)__shfl((int)u1[2*w],   srcA), bb1 = (uint32_t)__shfl((int)u1[2*w+1], srcA);
        uint32_t aa2 = (uint32_t)__shfl((int)u0[2*w],   srcB), bb2 = (uint32_t)__shfl((int)u0[2*w+1], srcB);
        uint32_t aa3 = (uint32_t)__shfl((int)u1[2*w],   srcB), bb3 = (uint32_t)__shfl((int)u1[2*w+1], srcB);
        FragU f;
        f.u[0] = hiq ? bb0 : aa0;
        f.u[1] = hiq ? bb1 : aa1;
        f.u[2] = hiq ? bb2 : aa2;
        f.u[3] = hiq ? bb3 : aa3;
        bA3[w] = f.v;
    }

    f32x4 acc3[4] = {};
    #pragma unroll
    for (int ct = 0; ct < 4; ++ct)
        #pragma unroll
        for (int kt = 0; kt < 2; ++kt) {
            bf16x8 b = *(const bf16x8*)(pW2 + (((ct * 2) + kt) << 9) + (lane << 3));
            acc3[ct] = __builtin_amdgcn_mfma_f32_16x16x32_bf16(bA3[kt], b, acc3[ct], 0, 0, 0);
        }
    #pragma unroll
    for (int ct = 0; ct < 4; ++ct) {
        float bb = b2[ct * 16 + m];
        #pragma unroll
        for (int rg = 0; rg < 4; ++rg) {
            int n = n0 + q * 4 + rg;
            if (n < N) out[(size_t)n * D + ct * 16 + m] = acc3[ct][rg] + bb;
        }
    }
}

extern "C" void kernel_launch(void* const* d_in, const int* in_sizes, int n_in,
                              void* d_out, int out_size, void* d_ws, size_t ws_size,
                              hipStream_t stream) {
    const int*   user_ids   = (const int*)  d_in[0];
    const int*   item_ids   = (const int*)  d_in[1];
    const int*   gender     = (const int*)  d_in[2];
    const int*   genres     = (const int*)  d_in[3];
    const int*   edge_user  = (const int*)  d_in[4];
    const int*   edge_item  = (const int*)  d_in[5];
    const int*   rating     = (const int*)  d_in[6];
    const float* user_emb   = (const float*)d_in[7];
    const float* item_emb   = (const float*)d_in[8];
    const float* gender_emb = (const float*)d_in[9];
    const float* genre_emb  = (const float*)d_in[10];
    const float* Wr_watched   = (const float*)d_in[11];
    const float* Wr_watchedby = (const float*)d_in[12];
    const float* Ww  = (const float*)d_in[13];
    const float* bw  = (const float*)d_in[14];
    const float* Wwb = (const float*)d_in[15];
    const float* bwb = (const float*)d_in[16];
    const float* Wf  = (const float*)d_in[17];
    const float* bf  = (const float*)d_in[18];
    const float* Vf  = (const float*)d_in[19];
    const float* bv  = (const float*)d_in[20];

    const int NU = in_sizes[0];
    const int NI = in_sizes[1];
    const int E  = in_sizes[4];
    const int NBI = (NI + 255) >> 8;   // coarse buckets (shift 8)
    const int NBU = (NU + 511) >> 9;   // coarse buckets (shift 9)

    float* out_f    = (float*)d_out;
    float* user_out = out_f;                       // [NU,64]
    float* item_out = out_f + (size_t)NU * D;      // [NI,64]

    // ws layout (bf16 first): hu, hi, hn1, hn2, y1, y2, packs, ints, staged x2
    unsigned short* hu  = (unsigned short*)d_ws;
    unsigned short* hi  = hu  + (size_t)NU * D;
    unsigned short* hn1 = hi  + (size_t)NI * D;            // items' agg
    unsigned short* hn2 = hn1 + (size_t)NI * D;            // users' agg
    unsigned short* y1  = hn2 + (size_t)NU * D;            // [6][NU][64]
    unsigned short* y2  = y1  + (size_t)NRAT * NU * D;     // [6][NI][64]
    size_t bfElems = (size_t)(2 * NU + 2 * NI) * D + (size_t)NRAT * (NU + NI) * D;
    size_t byteOff = (bfElems * 2 + 15) & ~(size_t)15;
    short* pWrW  = (short*)((char*)d_ws + byteOff);
    short* pWrWB = pWrW  + 24576;
    short* pWw   = pWrWB + 24576;
    short* pWwb  = pWw   + 8192;
    short* pVf   = pWwb  + 8192;
    short* pWf   = pVf   + 4096;
    int* coarseCntI = (int*)(pWf + 4096);   // 256, start of zeroRegion
    int* coarseCntU = coarseCntI + 256;     // 256, end of zeroRegion (512 ints)
    int* coarseOffI = coarseCntU + 256;     // 257
    int* coarseOffU = coarseOffI + 257;     // 257
    int* coarseCurI = coarseOffU + 257;     // 256
    int* coarseCurU = coarseCurI + 256;     // 256
    int* offI   = coarseCurU + 256;         // NI+1
    int* offU   = offI + NI + 1;            // NU+1
    unsigned* staged1 = (unsigned*)(offU + NU + 1);  // E
    unsigned* staged2 = staged1 + E;                 // E

    // 1. setup: node features + weight packing + counter zeroing (1 dispatch)
    int totalh = (NU + NI) * 16;
    build_setup<<<(totalh + 255) / 256, 256, 0, stream>>>(
        user_ids, item_ids, gender, genres,
        user_emb, item_emb, gender_emb, genre_emb, hu, hi, coarseCntI,
        Wr_watched, Wr_watchedby, Ww, Wwb, Vf, Wf,
        pWrW, pWrWB, pWw, pWwb, pVf, pWf, NU, NI);

    // 2. histogram + coarse scan
    hist_both<<<512, 256, 0, stream>>>(edge_item, edge_user, coarseCntI, coarseCntU, E);
    scan_both<<<2, 256, 0, stream>>>(coarseCntI, coarseCntU, coarseOffI, coarseOffU,
                                     coarseCurI, coarseCurU, NBI, NBU, E);

    // 3. sort both directions
    const int nTilesA = (E + 2047) / 2048;
    multisplit_A2<<<2 * nTilesA, 256, 0, stream>>>(edge_item, edge_user, rating,
                                                   coarseCurI, coarseCurU,
                                                   staged1, staged2, E, nTilesA, NU, NI);
    multisplit_B2<<<NBI + NBU, 256, 0, stream>>>(staged1, staged2, coarseOffI, coarseOffU,
                                                 offI, offU, NBI, NU, NI, E);

    // 4. pretransform both, gather both, transform both
    {
        int wavesU = (NU + 15) / 16, wavesI = (NI + 15) / 16;
        int blocks = (wavesU + wavesI + 3) / 4;
        pretransform2<<<blocks, 256, 0, stream>>>(hu, hi, pWrW, pWrWB, y1, y2, NU, NI, wavesU);
    }
    gather_both<<<(NI + NU + 3) / 4, 256, 0, stream>>>(offI, offU, staged1, staged2,
                                                       (const unsigned*)y1, (const unsigned*)y2,
                                                       (unsigned*)hn1, (unsigned*)hn2, NI, NU);
    {
        int tilesI = (NI + 15) / 16, tilesU = (NU + 15) / 16;
        int blocks = (tilesI + tilesU + 3) / 4;
        transform_both<<<blocks, 256, 0, stream>>>(hn1, hn2, hi, hu, pWw, pWwb, bw, bwb,
                                                   pVf, pWf, bv, bf, item_out, user_out,
                                                   NI, NU, tilesI);
    }
}

// Round 13
// 236.282 us; speedup vs baseline: 1.1298x; 1.0014x over previous
//
#include <hip/hip_runtime.h>
#include <hip/hip_bf16.h>

#define D 64
#define NRAT 6

typedef float f32x4 __attribute__((ext_vector_type(4)));
typedef short bf16x8 __attribute__((ext_vector_type(8)));

union FragU { uint32_t u[4]; bf16x8 v; };

__device__ __forceinline__ short f2bf(float f) {
    __hip_bfloat16 h = __float2bfloat16(f);
    union { __hip_bfloat16 h; short s; } c; c.h = h; return c.s;
}
__device__ __forceinline__ uint32_t pk2(float a, float b) {
    union { short s[2]; uint32_t u; } c; c.s[0] = f2bf(a); c.s[1] = f2bf(b); return c.u;
}

// Fused setup: (a) t<512 zero coarse counters; (b) node features hu/hi in
// bf16; (c) threads [1024,1024+73728) pack all weights to MFMA frag order.
__global__ void build_setup(const int* __restrict__ uid, const int* __restrict__ iid,
                            const int* __restrict__ gender, const int* __restrict__ genres,
                            const float* __restrict__ user_emb, const float* __restrict__ item_emb,
                            const float* __restrict__ gender_emb, const float* __restrict__ genre_emb,
                            unsigned short* __restrict__ hu, unsigned short* __restrict__ hi,
                            int* __restrict__ zeroRegion,
                            const float* __restrict__ Wr_w, const float* __restrict__ Wr_wb,
                            const float* __restrict__ Ww, const float* __restrict__ Wwb,
                            const float* __restrict__ Vf, const float* __restrict__ Wf,
                            short* __restrict__ pWrW, short* __restrict__ pWrWB,
                            short* __restrict__ pWw, short* __restrict__ pWwb,
                            short* __restrict__ pVf, short* __restrict__ pWf,
                            int NU, int NI) {
    int t = blockIdx.x * blockDim.x + threadIdx.x;
    if (t < 512) zeroRegion[t] = 0;      // cntI(256) + cntU(256)

    int tp = t - 1024;
    if (tp >= 0 && tp < 73728) {
        const float* src; short* dst; int K; int idx;
        if      (tp < 24576) { src = Wr_w;  dst = pWrW;  K = 64;  idx = tp; }
        else if (tp < 49152) { src = Wr_wb; dst = pWrWB; K = 64;  idx = tp - 24576; }
        else if (tp < 57344) { src = Ww;    dst = pWw;   K = 128; idx = tp - 49152; }
        else if (tp < 65536) { src = Wwb;   dst = pWwb;  K = 128; idx = tp - 57344; }
        else if (tp < 69632) { src = Vf;    dst = pVf;   K = 64;  idx = tp - 65536; }
        else                 { src = Wf;    dst = pWf;   K = 64;  idx = tp - 69632; }
        int per  = 64 * K;
        int sub  = idx / per;
        int li   = idx % per;
        int e    = li & 7;
        int lane = (li >> 3) & 63;
        int frag = li >> 9;
        int nkt  = K >> 5;
        int t16  = frag / nkt, tk = frag % nkt;
        int row  = t16 * 16 + (lane & 15);
        int col  = tk * 32 + (lane >> 4) * 8 + e;
        dst[idx] = f2bf(src[((size_t)(sub * 64 + row)) * K + col]);
    }

    int total = (NU + NI) * 16;          // one float4 (4 dims) per thread
    if (t >= total) return;
    int row = t >> 4, c = t & 15;
    uint2 o;
    if (row < NU) {
        int u = uid[row], g = gender[row];
        float4 a = ((const float4*)user_emb)[(size_t)u * 16 + c];
        float4 b = ((const float4*)gender_emb)[(size_t)g * 16 + c];
        o.x = pk2(a.x + b.x, a.y + b.y); o.y = pk2(a.z + b.z, a.w + b.w);
        ((uint2*)hu)[(size_t)row * 16 + c] = o;
    } else {
        int r2 = row - NU;
        int it = iid[r2], ge = genres[r2];
        float4 a = ((const float4*)item_emb)[(size_t)it * 16 + c];
        float4 b = ((const float4*)genre_emb)[(size_t)ge * 16 + c];
        o.x = pk2(a.x + b.x, a.y + b.y); o.y = pk2(a.z + b.z, a.w + b.w);
        ((uint2*)hi)[(size_t)r2 * 16 + c] = o;
    }
}

// One pass over both edge arrays: LDS hists for items (>>8) and users (>>9).
__global__ __launch_bounds__(256) void hist_both(const int* __restrict__ edge_item,
                                                 const int* __restrict__ edge_user,
                                                 int* __restrict__ cntI, int* __restrict__ cntU,
                                                 int E) {
    __shared__ int hI[256], hU[256];
    hI[threadIdx.x] = 0; hU[threadIdx.x] = 0;
    __syncthreads();
    for (int i = blockIdx.x * blockDim.x + threadIdx.x; i < E; i += gridDim.x * blockDim.x) {
        atomicAdd(&hI[edge_item[i] >> 8], 1);
        atomicAdd(&hU[edge_user[i] >> 9], 1);
    }
    __syncthreads();
    int vi = hI[threadIdx.x], vu = hU[threadIdx.x];
    if (vi) atomicAdd(&cntI[threadIdx.x], vi);
    if (vu) atomicAdd(&cntU[threadIdx.x], vu);
}

// 2 blocks: block 0 scans items' coarse counts, block 1 users'.
__global__ __launch_bounds__(256) void scan_both(const int* __restrict__ cntI,
                                                 const int* __restrict__ cntU,
                                                 int* __restrict__ offI, int* __restrict__ offU,
                                                 int* __restrict__ curI, int* __restrict__ curU,
                                                 int NBI, int NBU, int E) {
    const int* cnt = blockIdx.x ? cntU : cntI;
    int* coarseOff  = blockIdx.x ? offU : offI;
    int* coarseCur  = blockIdx.x ? curU : curI;
    int NB          = blockIdx.x ? NBU : NBI;
    __shared__ int p[256];
    int tid = threadIdx.x;
    int v = (tid < NB) ? cnt[tid] : 0;
    p[tid] = v; __syncthreads();
    for (int dd = 1; dd < 256; dd <<= 1) {
        int a = (tid >= dd) ? p[tid - dd] : 0;
        __syncthreads();
        p[tid] += a;
        __syncthreads();
    }
    int excl = p[tid] - v;
    if (tid < NB) { coarseOff[tid] = excl; coarseCur[tid] = excl; }
    if (tid == 0) coarseOff[NB] = E;
}

// Merged launch: blocks [0, 2*nTiles) run multisplit pass A (both dirs);
// blocks beyond run the per-source pretransform y[r][s] = Wr[r] @ h[s]
// (independent work, hidden under the sort).
__global__ __launch_bounds__(256) void msA_pre(
        const int* __restrict__ edge_item, const int* __restrict__ edge_user,
        const int* __restrict__ rating,
        int* __restrict__ curI, int* __restrict__ curU,
        unsigned* __restrict__ staged1, unsigned* __restrict__ staged2,
        const unsigned short* __restrict__ hu, const unsigned short* __restrict__ hi,
        const short* __restrict__ pWrW, const short* __restrict__ pWrWB,
        unsigned short* __restrict__ y1, unsigned short* __restrict__ y2,
        int E, int nTiles, int NU, int NI, int wavesU) {
    __shared__ unsigned srt[2048];
    __shared__ int sft[2048];
    __shared__ int hist[256], pfx[256], shm[256];
    const int tid = threadIdx.x;

    if ((int)blockIdx.x >= 2 * nTiles) {
        // ---------------- pretransform section ----------------
        const int lane = tid & 63;
        const int m = lane & 15, q = lane >> 4;
        int wave = (((int)blockIdx.x - 2 * nTiles) * 256 + tid) >> 6;
        const bool dirI = wave >= wavesU;
        const unsigned short* h = dirI ? hi : hu;
        const short* pWr = dirI ? pWrWB : pWrW;
        unsigned short* y = dirI ? y2 : y1;
        const int Ns = dirI ? NI : NU;
        if (dirI) wave -= wavesU;
        const int n0 = wave * 16;
        if (n0 >= Ns) return;
        int nrow = n0 + m; if (nrow > Ns - 1) nrow = Ns - 1;

        bf16x8 bB[2];
        {
            const unsigned short* ph = h + (size_t)nrow * D + q * 8;
            bB[0] = *(const bf16x8*)(ph);
            bB[1] = *(const bf16x8*)(ph + 32);
        }
        const int srcA = ((q & 1) << 5) + m;
        const int srcB = srcA + 16;
        const bool hiq = (q >> 1) != 0;

        #pragma unroll
        for (int r = 0; r < NRAT; ++r) {
            f32x4 acc[4] = {};
            #pragma unroll
            for (int it = 0; it < 4; ++it)
                #pragma unroll
                for (int kt = 0; kt < 2; ++kt) {
                    bf16x8 a = *(const bf16x8*)(pWr + (((r * 4 + it) * 2 + kt) << 9) + (lane << 3));
                    acc[it] = __builtin_amdgcn_mfma_f32_16x16x32_bf16(a, bB[kt], acc[it], 0, 0, 0);
                }
            uint32_t u0[4], u1[4];
            #pragma unroll
            for (int it = 0; it < 4; ++it) {
                u0[it] = pk2(acc[it][0], acc[it][1]);
                u1[it] = pk2(acc[it][2], acc[it][3]);
            }
            #pragma unroll
            for (int w = 0; w < 2; ++w) {
                uint32_t aa0 = (uint32_t)__shfl((int)u0[2*w],   srcA), bb0 = (uint32_t)__shfl((int)u0[2*w+1], srcA);
                uint32_t aa1 = (uint32_t)__shfl((int)u1[2*w],   srcA), bb1 = (uint32_t)__shfl((int)u1[2*w+1], srcA);
                uint32_t aa2 = (uint32_t)__shfl((int)u0[2*w],   srcB), bb2 = (uint32_t)__shfl((int)u0[2*w+1], srcB);
                uint32_t aa3 = (uint32_t)__shfl((int)u1[2*w],   srcB), bb3 = (uint32_t)__shfl((int)u1[2*w+1], srcB);
                FragU f;
                f.u[0] = hiq ? bb0 : aa0;
                f.u[1] = hiq ? bb1 : aa1;
                f.u[2] = hiq ? bb2 : aa2;
                f.u[3] = hiq ? bb3 : aa3;
                *(bf16x8*)(y + ((size_t)r * Ns + nrow) * D + w * 32 + q * 8) = f.v;
            }
        }
        return;
    }

    // ---------------- multisplit pass A section ----------------
    const bool dirU = (int)blockIdx.x >= nTiles;
    const int* dst = dirU ? edge_user : edge_item;
    const int* src = dirU ? edge_item : edge_user;
    const int shift = dirU ? 9 : 8;
    const int Ns = dirU ? NI : NU;
    int* coarseCur = dirU ? curU : curI;
    unsigned* staged = dirU ? staged2 : staged1;
    const int tile = (dirU ? (int)blockIdx.x - nTiles : (int)blockIdx.x) * 2048;

    int cnt = E - tile; if (cnt > 2048) cnt = 2048;
    hist[tid] = 0;
    __syncthreads();
    unsigned rec[8]; int bk[8];
    #pragma unroll
    for (int k = 0; k < 8; ++k) {
        int i = tile + k * 256 + tid;
        bk[k] = -1;
        if (i < E) {
            int d = dst[i], s = src[i], r = rating[i];
            bk[k] = d >> shift;
            rec[k] = (unsigned)(s + r * Ns) | ((unsigned)(d & ((1 << shift) - 1)) << 20);
            atomicAdd(&hist[bk[k]], 1);
        }
    }
    __syncthreads();
    pfx[tid] = hist[tid];
    __syncthreads();
    for (int dd = 1; dd < 256; dd <<= 1) {
        int a = (tid >= dd) ? pfx[tid - dd] : 0;
        __syncthreads();
        pfx[tid] += a;
        __syncthreads();
    }
    int h = hist[tid];
    int excl = pfx[tid] - h;
    int gb = 0;
    if (h > 0) gb = atomicAdd(&coarseCur[tid], h);
    shm[tid] = gb - excl;
    __syncthreads();
    hist[tid] = excl;          // reuse as local cursor
    __syncthreads();
    #pragma unroll
    for (int k = 0; k < 8; ++k) {
        if (bk[k] >= 0) {
            int p = atomicAdd(&hist[bk[k]], 1);
            srt[p] = rec[k];
            sft[p] = shm[bk[k]];
        }
    }
    __syncthreads();
    for (int i = tid; i < cnt; i += 256)
        staged[sft[i] + i] = srt[i];
}

// Pass B, both directions: one block per coarse bucket.
__global__ __launch_bounds__(256) void multisplit_B2(
        unsigned* __restrict__ staged1, unsigned* __restrict__ staged2,
        const int* __restrict__ coarseOffI, const int* __restrict__ coarseOffU,
        int* __restrict__ offI, int* __restrict__ offU,
        int NBI, int NU, int NI, int E) {
    const bool dirU = (int)blockIdx.x >= NBI;
    unsigned* staged = dirU ? staged2 : staged1;
    const int* coarseOff = dirU ? coarseOffU : coarseOffI;
    int* off = dirU ? offU : offI;
    const int N = dirU ? NU : NI;
    const int shift = dirU ? 9 : 8;
    const int b = dirU ? blockIdx.x - NBI : blockIdx.x;
    const int nb = dirU ? (N + (1 << 9) - 1) >> 9 : NBI;

    __shared__ unsigned rec[16384];
    __shared__ int hist[512], pfx[512];
    const int tid = threadIdx.x;
    const int range = 1 << shift;
    int cbase = coarseOff[b];
    int cnt = coarseOff[b + 1] - cbase;
    if (cnt > 16384) cnt = 16384;   // safety guard (never expected)
    hist[tid] = 0; hist[tid + 256] = 0;
    __syncthreads();
    for (int i = tid; i < cnt; i += 256) {
        unsigned x = staged[cbase + i];
        rec[i] = x;
        atomicAdd(&hist[x >> 20], 1);
    }
    __syncthreads();
    pfx[tid] = hist[tid]; pfx[tid + 256] = hist[tid + 256];
    __syncthreads();
    for (int dd = 1; dd < 256; dd <<= 1) {
        int a = (tid >= dd) ? pfx[tid - dd] : 0;
        int c = (tid >= dd) ? pfx[tid + 256 - dd] : 0;
        __syncthreads();
        pfx[tid] += a; pfx[tid + 256] += c;
        __syncthreads();
    }
    int tot0 = pfx[255];
    __syncthreads();
    pfx[tid + 256] += tot0;
    __syncthreads();
    int e0 = pfx[tid] - hist[tid];
    int e1 = pfx[tid + 256] - hist[tid + 256];
    __syncthreads();
    hist[tid] = e0; hist[tid + 256] = e1;   // cursors
    int dbase = b << shift;
    if (dbase + tid < N) off[dbase + tid] = cbase + e0;
    if (range > 256 && dbase + tid + 256 < N) off[dbase + tid + 256] = cbase + e1;
    if (b == nb - 1 && tid == 0) off[N] = E;
    __syncthreads();
    for (int i = tid; i < cnt; i += 256) {
        unsigned x = rec[i];
        int p = atomicAdd(&hist[x >> 20], 1);
        staged[cbase + p] = x;
    }
}

// One wave per dst node, both directions. 4 edges per iteration: quarter q
// (16 lanes) reads edge j+q's 128B y-row as uint2 (4 dims/lane). Cross-
// quarter shfl_xor combine at the end; quarter-0 stores hn row as uint2.
__global__ __launch_bounds__(256) void gather_both(
        const int* __restrict__ offI, const int* __restrict__ offU,
        const unsigned* __restrict__ staged1, const unsigned* __restrict__ staged2,
        const uint2* __restrict__ y1, const uint2* __restrict__ y2,
        uint2* __restrict__ hn1, uint2* __restrict__ hn2,
        int NI, int NU) {
    const int lane = threadIdx.x & 63;
    const int qt = lane >> 4;            // quarter 0..3
    const int t  = lane & 15;            // dims 4t..4t+3
    int g = (blockIdx.x * blockDim.x + threadIdx.x) >> 6;
    const bool dirU = g >= NI;
    int n = dirU ? g - NI : g;
    if (dirU && n >= NU) return;
    const int* off = dirU ? offU : offI;
    const unsigned* packed = dirU ? staged2 : staged1;
    const uint2* y = dirU ? y2 : y1;     // row = 16 uint2
    uint2* hn = dirU ? hn2 : hn1;        // row = 16 uint2

    int b = off[n], e = off[n + 1];
    float a0 = 0.f, a1 = 0.f, a2 = 0.f, a3 = 0.f;

#define YROW(mm) y[(((mm) & 0xFFFFFu) << 4) | (unsigned)t]
#define ACC4(dd) { a0 += __uint_as_float((dd).x << 16);          \
                   a1 += __uint_as_float((dd).x & 0xFFFF0000u);  \
                   a2 += __uint_as_float((dd).y << 16);          \
                   a3 += __uint_as_float((dd).y & 0xFFFF0000u); }

    for (int base = b; base < e; base += 64) {
        int idx = base + lane; if (idx > e - 1) idx = e - 1;
        unsigned meta = packed[idx];
        int cnt = e - base; if (cnt > 64) cnt = 64;
        int j = 0;
        for (; j + 4 <= cnt; j += 4) {
            unsigned mm = (unsigned)__shfl((int)meta, j + qt);
            uint2 dd = YROW(mm);
            ACC4(dd);
        }
        int rem = cnt - j;
        if (rem > 0) {
            unsigned mm = (unsigned)__shfl((int)meta, j + qt);  // clamped meta valid
            uint2 dd = YROW(mm);
            if (qt < rem) { ACC4(dd); }
        }
    }
#undef YROW
#undef ACC4

    // combine the 4 quarters (lanes t, t+16, t+32, t+48 hold same dims)
    a0 += __shfl_xor(a0, 16); a1 += __shfl_xor(a1, 16);
    a2 += __shfl_xor(a2, 16); a3 += __shfl_xor(a3, 16);
    a0 += __shfl_xor(a0, 32); a1 += __shfl_xor(a1, 32);
    a2 += __shfl_xor(a2, 32); a3 += __shfl_xor(a3, 32);

    float inv = 1.0f / fmaxf((float)(e - b), 1.0f);
    if (lane < 16) {
        uint2 o;
        o.x = pk2(a0 * inv, a1 * inv);
        o.y = pk2(a2 * inv, a3 * inv);
        hn[(size_t)n * 16 + t] = o;
    }
}

// Per-16-node-tile MFMA transform, both directions:
//   GEMM2 (transposed): h2^T = relu(Wlin @ [hd|hn]^T + blin)
//   GEMM3 (normal):     out  = h2 @ W2^T + b2
__global__ __launch_bounds__(256) void transform_both(
        const unsigned short* __restrict__ hn1, const unsigned short* __restrict__ hn2,
        const unsigned short* __restrict__ hi, const unsigned short* __restrict__ hu,
        const short* __restrict__ pWw, const short* __restrict__ pWwb,
        const float* __restrict__ bw, const float* __restrict__ bwb,
        const short* __restrict__ pVf, const short* __restrict__ pWf,
        const float* __restrict__ bv, const float* __restrict__ bf,
        float* __restrict__ item_out, float* __restrict__ user_out,
        int NI, int NU, int tilesI) {
    const int lane = threadIdx.x & 63;
    const int m = lane & 15, q = lane >> 4;
    int wave = (blockIdx.x * blockDim.x + threadIdx.x) >> 6;
    const bool dirU = wave >= tilesI;
    if (dirU) wave -= tilesI;
    const unsigned short* hn = dirU ? hn2 : hn1;
    const unsigned short* hd = dirU ? hu : hi;
    const short* pWlin = dirU ? pWwb : pWw;
    const float* blin  = dirU ? bwb : bw;
    const short* pW2   = dirU ? pWf : pVf;
    const float* b2    = dirU ? bf : bv;
    float* out = dirU ? user_out : item_out;
    const int N = dirU ? NU : NI;
    const int n0 = wave * 16;
    if (n0 >= N) return;
    int nrow = n0 + m; if (nrow > N - 1) nrow = N - 1;

    bf16x8 bH[2], bHN[2];
    {
        const unsigned short* ph = hd + (size_t)nrow * D + q * 8;
        bH[0] = *(const bf16x8*)(ph);
        bH[1] = *(const bf16x8*)(ph + 32);
        const unsigned short* pn = hn + (size_t)nrow * D + q * 8;
        bHN[0] = *(const bf16x8*)(pn);
        bHN[1] = *(const bf16x8*)(pn + 32);
    }

    f32x4 acc2[4] = {};
    #pragma unroll
    for (int it = 0; it < 4; ++it)
        #pragma unroll
        for (int kt = 0; kt < 4; ++kt) {
            bf16x8 a = *(const bf16x8*)(pWlin + (((it * 4) + kt) << 9) + (lane << 3));
            bf16x8 b = (kt < 2) ? bH[kt] : bHN[kt - 2];
            acc2[it] = __builtin_amdgcn_mfma_f32_16x16x32_bf16(a, b, acc2[it], 0, 0, 0);
        }

    const int srcA = ((q & 1) << 5) + m;
    const int srcB = srcA + 16;
    const bool hiq = (q >> 1) != 0;
    uint32_t u0[4], u1[4];
    float vbl = blin[lane];
    #pragma unroll
    for (int it = 0; it < 4; ++it) {
        float h0 = fmaxf(acc2[it][0] + __shfl(vbl, it * 16 + q * 4 + 0), 0.f);
        float h1 = fmaxf(acc2[it][1] + __shfl(vbl, it * 16 + q * 4 + 1), 0.f);
        float h2 = fmaxf(acc2[it][2] + __shfl(vbl, it * 16 + q * 4 + 2), 0.f);
        float h3 = fmaxf(acc2[it][3] + __shfl(vbl, it * 16 + q * 4 + 3), 0.f);
        u0[it] = pk2(h0, h1);
        u1[it] = pk2(h2, h3);
    }
    bf16x8 bA3[2];
    #pragma unroll
    for (int w = 0; w < 2; ++w) {
        uint32_t aa0 = (uint32_t)__shfl((int)u0[2*w],   srcA), bb0 = (uint32_t)__shfl((int)u0[2*w+1], srcA);
        uint32_t aa1 = (uint32_t)__shfl((int)u1[2*w],   srcA), bb1 = (uint32_t)__shfl((int)u1[2*w+1], srcA);
        uint32_t aa2 = (uint32_t)__shfl((int)u0[2*w],   srcB), bb2 = (uint32_t)__shfl((int)u0[2*w+1], srcB);
        uint32_t aa3 = (uint32_t)__shfl((int)u1[2*w],   srcB), bb3 = (uint32_t)__shfl((int)u1[2*w+1], srcB);
        FragU f;
        f.u[0] = hiq ? bb0 : aa0;
        f.u[1] = hiq ? bb1 : aa1;
        f.u[2] = hiq ? bb2 : aa2;
        f.u[3] = hiq ? bb3 : aa3;
        bA3[w] = f.v;
    }

    f32x4 acc3[4] = {};
    #pragma unroll
    for (int ct = 0; ct < 4; ++ct)
        #pragma unroll
        for (int kt = 0; kt < 2; ++kt) {
            bf16x8 b = *(const bf16x8*)(pW2 + (((ct * 2) + kt) << 9) + (lane << 3));
            acc3[ct] = __builtin_amdgcn_mfma_f32_16x16x32_bf16(bA3[kt], b, acc3[ct], 0, 0, 0);
        }
    #pragma unroll
    for (int ct = 0; ct < 4; ++ct) {
        float bb = b2[ct * 16 + m];
        #pragma unroll
        for (int rg = 0; rg < 4; ++rg) {
            int n = n0 + q * 4 + rg;
            if (n < N) out[(size_t)n * D + ct * 16 + m] = acc3[ct][rg] + bb;
        }
    }
}

extern "C" void kernel_launch(void* const* d_in, const int* in_sizes, int n_in,
                              void* d_out, int out_size, void* d_ws, size_t ws_size,
                              hipStream_t stream) {
    const int*   user_ids   = (const int*)  d_in[0];
    const int*   item_ids   = (const int*)  d_in[1];
    const int*   gender     = (const int*)  d_in[2];
    const int*   genres     = (const int*)  d_in[3];
    const int*   edge_user  = (const int*)  d_in[4];
    const int*   edge_item  = (const int*)  d_in[5];
    const int*   rating     = (const int*)  d_in[6];
    const float* user_emb   = (const float*)d_in[7];
    const float* item_emb   = (const float*)d_in[8];
    const float* gender_emb = (const float*)d_in[9];
    const float* genre_emb  = (const float*)d_in[10];
    const float* Wr_watched   = (const float*)d_in[11];
    const float* Wr_watchedby = (const float*)d_in[12];
    const float* Ww  = (const float*)d_in[13];
    const float* bw  = (const float*)d_in[14];
    const float* Wwb = (const float*)d_in[15];
    const float* bwb = (const float*)d_in[16];
    const float* Wf  = (const float*)d_in[17];
    const float* bf  = (const float*)d_in[18];
    const float* Vf  = (const float*)d_in[19];
    const float* bv  = (const float*)d_in[20];

    const int NU = in_sizes[0];
    const int NI = in_sizes[1];
    const int E  = in_sizes[4];
    const int NBI = (NI + 255) >> 8;   // coarse buckets (shift 8)
    const int NBU = (NU + 511) >> 9;   // coarse buckets (shift 9)

    float* out_f    = (float*)d_out;
    float* user_out = out_f;                       // [NU,64]
    float* item_out = out_f + (size_t)NU * D;      // [NI,64]

    // ws layout (bf16 first): hu, hi, hn1, hn2, y1, y2, packs, ints, staged x2
    unsigned short* hu  = (unsigned short*)d_ws;
    unsigned short* hi  = hu  + (size_t)NU * D;
    unsigned short* hn1 = hi  + (size_t)NI * D;            // items' agg
    unsigned short* hn2 = hn1 + (size_t)NI * D;            // users' agg
    unsigned short* y1  = hn2 + (size_t)NU * D;            // [6][NU][64]
    unsigned short* y2  = y1  + (size_t)NRAT * NU * D;     // [6][NI][64]
    size_t bfElems = (size_t)(2 * NU + 2 * NI) * D + (size_t)NRAT * (NU + NI) * D;
    size_t byteOff = (bfElems * 2 + 15) & ~(size_t)15;
    short* pWrW  = (short*)((char*)d_ws + byteOff);
    short* pWrWB = pWrW  + 24576;
    short* pWw   = pWrWB + 24576;
    short* pWwb  = pWw   + 8192;
    short* pVf   = pWwb  + 8192;
    short* pWf   = pVf   + 4096;
    int* coarseCntI = (int*)(pWf + 4096);   // 256, start of zeroRegion
    int* coarseCntU = coarseCntI + 256;     // 256, end of zeroRegion (512 ints)
    int* coarseOffI = coarseCntU + 256;     // 257
    int* coarseOffU = coarseOffI + 257;     // 257
    int* coarseCurI = coarseOffU + 257;     // 256
    int* coarseCurU = coarseCurI + 256;     // 256
    int* offI   = coarseCurU + 256;         // NI+1
    int* offU   = offI + NI + 1;            // NU+1
    unsigned* staged1 = (unsigned*)(offU + NU + 1);  // E
    unsigned* staged2 = staged1 + E;                 // E

    // 1. setup: node features + weight packing + counter zeroing
    int totalh = (NU + NI) * 16;
    build_setup<<<(totalh + 255) / 256, 256, 0, stream>>>(
        user_ids, item_ids, gender, genres,
        user_emb, item_emb, gender_emb, genre_emb, hu, hi, coarseCntI,
        Wr_watched, Wr_watchedby, Ww, Wwb, Vf, Wf,
        pWrW, pWrWB, pWw, pWwb, pVf, pWf, NU, NI);

    // 2. histogram + coarse scan
    hist_both<<<512, 256, 0, stream>>>(edge_item, edge_user, coarseCntI, coarseCntU, E);
    scan_both<<<2, 256, 0, stream>>>(coarseCntI, coarseCntU, coarseOffI, coarseOffU,
                                     coarseCurI, coarseCurU, NBI, NBU, E);

    // 3. sort pass A (both dirs) + pretransform (hidden) in one launch
    const int nTilesA = (E + 2047) / 2048;
    const int wavesU = (NU + 15) / 16, wavesI = (NI + 15) / 16;
    const int ptBlocks = (wavesU + wavesI + 3) / 4;
    msA_pre<<<2 * nTilesA + ptBlocks, 256, 0, stream>>>(
        edge_item, edge_user, rating, coarseCurI, coarseCurU, staged1, staged2,
        hu, hi, pWrW, pWrWB, y1, y2, E, nTilesA, NU, NI, wavesU);

    // 4. sort pass B (both dirs)
    multisplit_B2<<<NBI + NBU, 256, 0, stream>>>(staged1, staged2, coarseOffI, coarseOffU,
                                                 offI, offU, NBI, NU, NI, E);

    // 5. gather both, transform both
    gather_both<<<(NI + NU + 3) / 4, 256, 0, stream>>>(offI, offU, staged1, staged2,
                                                       (const uint2*)y1, (const uint2*)y2,
                                                       (uint2*)hn1, (uint2*)hn2, NI, NU);
    {
        int tilesI = (NI + 15) / 16, tilesU = (NU + 15) / 16;
        int blocks = (tilesI + tilesU + 3) / 4;
        transform_both<<<blocks, 256, 0, stream>>>(hn1, hn2, hi, hu, pWw, pWwb, bw, bwb,
                                                   pVf, pWf, bv, bf, item_out, user_out,
                                                   NI, NU, tilesI);
    }
}

// Round 14
// 210.377 us; speedup vs baseline: 1.2689x; 1.1231x over previous
//
#include <hip/hip_runtime.h>
#include <hip/hip_bf16.h>

#define D 64
#define NRAT 6
#define TILE_A 4096

typedef float f32x4 __attribute__((ext_vector_type(4)));
typedef short bf16x8 __attribute__((ext_vector_type(8)));

union FragU { uint32_t u[4]; bf16x8 v; };

__device__ __forceinline__ short f2bf(float f) {
    __hip_bfloat16 h = __float2bfloat16(f);
    union { __hip_bfloat16 h; short s; } c; c.h = h; return c.s;
}
__device__ __forceinline__ uint32_t pk2(float a, float b) {
    union { short s[2]; uint32_t u; } c; c.s[0] = f2bf(a); c.s[1] = f2bf(b); return c.u;
}

// Fused setup: (a) first 512 blocks also histogram both edge arrays (LDS
// hists, merged by atomics into pre-zeroed cntI/cntU); (b) node features
// hu/hi in bf16; (c) threads [1024,1024+73728) pack weights to MFMA order.
__global__ void build_setup(const int* __restrict__ uid, const int* __restrict__ iid,
                            const int* __restrict__ gender, const int* __restrict__ genres,
                            const float* __restrict__ user_emb, const float* __restrict__ item_emb,
                            const float* __restrict__ gender_emb, const float* __restrict__ genre_emb,
                            unsigned short* __restrict__ hu, unsigned short* __restrict__ hi,
                            const int* __restrict__ edge_item, const int* __restrict__ edge_user,
                            int* __restrict__ cntI, int* __restrict__ cntU, int E,
                            const float* __restrict__ Wr_w, const float* __restrict__ Wr_wb,
                            const float* __restrict__ Ww, const float* __restrict__ Wwb,
                            const float* __restrict__ Vf, const float* __restrict__ Wf,
                            short* __restrict__ pWrW, short* __restrict__ pWrWB,
                            short* __restrict__ pWw, short* __restrict__ pWwb,
                            short* __restrict__ pVf, short* __restrict__ pWf,
                            int NU, int NI) {
    // ---- edge histogram on first 512 blocks (block-uniform branch) ----
    if (blockIdx.x < 512) {
        __shared__ int hI[256], hU[256];
        hI[threadIdx.x] = 0; hU[threadIdx.x] = 0;
        __syncthreads();
        for (int i = blockIdx.x * 256 + threadIdx.x; i < E; i += 512 * 256) {
            atomicAdd(&hI[edge_item[i] >> 8], 1);
            atomicAdd(&hU[edge_user[i] >> 9], 1);
        }
        __syncthreads();
        int vi = hI[threadIdx.x], vu = hU[threadIdx.x];
        if (vi) atomicAdd(&cntI[threadIdx.x], vi);
        if (vu) atomicAdd(&cntU[threadIdx.x], vu);
    }

    int t = blockIdx.x * blockDim.x + threadIdx.x;

    // ---- weight packing on threads [1024, 1024+73728) ----
    int tp = t - 1024;
    if (tp >= 0 && tp < 73728) {
        const float* src; short* dst; int K; int idx;
        if      (tp < 24576) { src = Wr_w;  dst = pWrW;  K = 64;  idx = tp; }
        else if (tp < 49152) { src = Wr_wb; dst = pWrWB; K = 64;  idx = tp - 24576; }
        else if (tp < 57344) { src = Ww;    dst = pWw;   K = 128; idx = tp - 49152; }
        else if (tp < 65536) { src = Wwb;   dst = pWwb;  K = 128; idx = tp - 57344; }
        else if (tp < 69632) { src = Vf;    dst = pVf;   K = 64;  idx = tp - 65536; }
        else                 { src = Wf;    dst = pWf;   K = 64;  idx = tp - 69632; }
        int per  = 64 * K;
        int sub  = idx / per;
        int li   = idx % per;
        int e    = li & 7;
        int lane = (li >> 3) & 63;
        int frag = li >> 9;
        int nkt  = K >> 5;
        int t16  = frag / nkt, tk = frag % nkt;
        int row  = t16 * 16 + (lane & 15);
        int col  = tk * 32 + (lane >> 4) * 8 + e;
        dst[idx] = f2bf(src[((size_t)(sub * 64 + row)) * K + col]);
    }

    // ---- node features ----
    int total = (NU + NI) * 16;          // one float4 (4 dims) per thread
    if (t >= total) return;
    int row = t >> 4, c = t & 15;
    uint2 o;
    if (row < NU) {
        int u = uid[row], g = gender[row];
        float4 a = ((const float4*)user_emb)[(size_t)u * 16 + c];
        float4 b = ((const float4*)gender_emb)[(size_t)g * 16 + c];
        o.x = pk2(a.x + b.x, a.y + b.y); o.y = pk2(a.z + b.z, a.w + b.w);
        ((uint2*)hu)[(size_t)row * 16 + c] = o;
    } else {
        int r2 = row - NU;
        int it = iid[r2], ge = genres[r2];
        float4 a = ((const float4*)item_emb)[(size_t)it * 16 + c];
        float4 b = ((const float4*)genre_emb)[(size_t)ge * 16 + c];
        o.x = pk2(a.x + b.x, a.y + b.y); o.y = pk2(a.z + b.z, a.w + b.w);
        ((uint2*)hi)[(size_t)r2 * 16 + c] = o;
    }
}

// 2 blocks: block 0 scans items' coarse counts, block 1 users'.
__global__ __launch_bounds__(256) void scan_both(const int* __restrict__ cntI,
                                                 const int* __restrict__ cntU,
                                                 int* __restrict__ offI, int* __restrict__ offU,
                                                 int* __restrict__ curI, int* __restrict__ curU,
                                                 int NBI, int NBU, int E) {
    const int* cnt = blockIdx.x ? cntU : cntI;
    int* coarseOff  = blockIdx.x ? offU : offI;
    int* coarseCur  = blockIdx.x ? curU : curI;
    int NB          = blockIdx.x ? NBU : NBI;
    __shared__ int p[256];
    int tid = threadIdx.x;
    int v = (tid < NB) ? cnt[tid] : 0;
    p[tid] = v; __syncthreads();
    for (int dd = 1; dd < 256; dd <<= 1) {
        int a = (tid >= dd) ? p[tid - dd] : 0;
        __syncthreads();
        p[tid] += a;
        __syncthreads();
    }
    int excl = p[tid] - v;
    if (tid < NB) { coarseOff[tid] = excl; coarseCur[tid] = excl; }
    if (tid == 0) coarseOff[NB] = E;
}

// Merged launch: blocks [0, 2*nTiles) run multisplit pass A (both dirs,
// TILE_A=4096 edges/tile); blocks beyond run the per-source pretransform
// y[r][s] = Wr[r] @ h[s] (independent work, hidden under the sort).
__global__ __launch_bounds__(256) void msA_pre(
        const int* __restrict__ edge_item, const int* __restrict__ edge_user,
        const int* __restrict__ rating,
        int* __restrict__ curI, int* __restrict__ curU,
        unsigned* __restrict__ staged1, unsigned* __restrict__ staged2,
        const unsigned short* __restrict__ hu, const unsigned short* __restrict__ hi,
        const short* __restrict__ pWrW, const short* __restrict__ pWrWB,
        unsigned short* __restrict__ y1, unsigned short* __restrict__ y2,
        int E, int nTiles, int NU, int NI, int wavesU) {
    __shared__ unsigned srt[TILE_A];
    __shared__ int sft[TILE_A];
    __shared__ int hist[256], pfx[256], shm[256];
    const int tid = threadIdx.x;

    if ((int)blockIdx.x >= 2 * nTiles) {
        // ---------------- pretransform section ----------------
        const int lane = tid & 63;
        const int m = lane & 15, q = lane >> 4;
        int wave = (((int)blockIdx.x - 2 * nTiles) * 256 + tid) >> 6;
        const bool dirI = wave >= wavesU;
        const unsigned short* h = dirI ? hi : hu;
        const short* pWr = dirI ? pWrWB : pWrW;
        unsigned short* y = dirI ? y2 : y1;
        const int Ns = dirI ? NI : NU;
        if (dirI) wave -= wavesU;
        const int n0 = wave * 16;
        if (n0 >= Ns) return;
        int nrow = n0 + m; if (nrow > Ns - 1) nrow = Ns - 1;

        bf16x8 bB[2];
        {
            const unsigned short* ph = h + (size_t)nrow * D + q * 8;
            bB[0] = *(const bf16x8*)(ph);
            bB[1] = *(const bf16x8*)(ph + 32);
        }
        const int srcA = ((q & 1) << 5) + m;
        const int srcB = srcA + 16;
        const bool hiq = (q >> 1) != 0;

        #pragma unroll
        for (int r = 0; r < NRAT; ++r) {
            f32x4 acc[4] = {};
            #pragma unroll
            for (int it = 0; it < 4; ++it)
                #pragma unroll
                for (int kt = 0; kt < 2; ++kt) {
                    bf16x8 a = *(const bf16x8*)(pWr + (((r * 4 + it) * 2 + kt) << 9) + (lane << 3));
                    acc[it] = __builtin_amdgcn_mfma_f32_16x16x32_bf16(a, bB[kt], acc[it], 0, 0, 0);
                }
            uint32_t u0[4], u1[4];
            #pragma unroll
            for (int it = 0; it < 4; ++it) {
                u0[it] = pk2(acc[it][0], acc[it][1]);
                u1[it] = pk2(acc[it][2], acc[it][3]);
            }
            #pragma unroll
            for (int w = 0; w < 2; ++w) {
                uint32_t aa0 = (uint32_t)__shfl((int)u0[2*w],   srcA), bb0 = (uint32_t)__shfl((int)u0[2*w+1], srcA);
                uint32_t aa1 = (uint32_t)__shfl((int)u1[2*w],   srcA), bb1 = (uint32_t)__shfl((int)u1[2*w+1], srcA);
                uint32_t aa2 = (uint32_t)__shfl((int)u0[2*w],   srcB), bb2 = (uint32_t)__shfl((int)u0[2*w+1], srcB);
                uint32_t aa3 = (uint32_t)__shfl((int)u1[2*w],   srcB), bb3 = (uint32_t)__shfl((int)u1[2*w+1], srcB);
                FragU f;
                f.u[0] = hiq ? bb0 : aa0;
                f.u[1] = hiq ? bb1 : aa1;
                f.u[2] = hiq ? bb2 : aa2;
                f.u[3] = hiq ? bb3 : aa3;
                *(bf16x8*)(y + ((size_t)r * Ns + nrow) * D + w * 32 + q * 8) = f.v;
            }
        }
        return;
    }

    // ---------------- multisplit pass A section ----------------
    const bool dirU = (int)blockIdx.x >= nTiles;
    const int* dst = dirU ? edge_user : edge_item;
    const int* src = dirU ? edge_item : edge_user;
    const int shift = dirU ? 9 : 8;
    const int Ns = dirU ? NI : NU;
    int* coarseCur = dirU ? curU : curI;
    unsigned* staged = dirU ? staged2 : staged1;
    const int tile = (dirU ? (int)blockIdx.x - nTiles : (int)blockIdx.x) * TILE_A;

    int cnt = E - tile; if (cnt > TILE_A) cnt = TILE_A;
    hist[tid] = 0;
    __syncthreads();
    unsigned rec[16]; int bk[16];
    #pragma unroll
    for (int k = 0; k < 16; ++k) {
        int i = tile + k * 256 + tid;
        bk[k] = -1;
        if (i < E) {
            int d = dst[i], s = src[i], r = rating[i];
            bk[k] = d >> shift;
            rec[k] = (unsigned)(s + r * Ns) | ((unsigned)(d & ((1 << shift) - 1)) << 20);
            atomicAdd(&hist[bk[k]], 1);
        }
    }
    __syncthreads();
    pfx[tid] = hist[tid];
    __syncthreads();
    for (int dd = 1; dd < 256; dd <<= 1) {
        int a = (tid >= dd) ? pfx[tid - dd] : 0;
        __syncthreads();
        pfx[tid] += a;
        __syncthreads();
    }
    int h = hist[tid];
    int excl = pfx[tid] - h;
    int gb = 0;
    if (h > 0) gb = atomicAdd(&coarseCur[tid], h);
    shm[tid] = gb - excl;
    __syncthreads();
    hist[tid] = excl;          // reuse as local cursor
    __syncthreads();
    #pragma unroll
    for (int k = 0; k < 16; ++k) {
        if (bk[k] >= 0) {
            int p = atomicAdd(&hist[bk[k]], 1);
            srt[p] = rec[k];
            sft[p] = shm[bk[k]];
        }
    }
    __syncthreads();
    for (int i = tid; i < cnt; i += 256)
        staged[sft[i] + i] = srt[i];
}

// Pass B, both directions: one block per coarse bucket.
__global__ __launch_bounds__(256) void multisplit_B2(
        unsigned* __restrict__ staged1, unsigned* __restrict__ staged2,
        const int* __restrict__ coarseOffI, const int* __restrict__ coarseOffU,
        int* __restrict__ offI, int* __restrict__ offU,
        int NBI, int NU, int NI, int E) {
    const bool dirU = (int)blockIdx.x >= NBI;
    unsigned* staged = dirU ? staged2 : staged1;
    const int* coarseOff = dirU ? coarseOffU : coarseOffI;
    int* off = dirU ? offU : offI;
    const int N = dirU ? NU : NI;
    const int shift = dirU ? 9 : 8;
    const int b = dirU ? blockIdx.x - NBI : blockIdx.x;
    const int nb = dirU ? (N + (1 << 9) - 1) >> 9 : NBI;

    __shared__ unsigned rec[16384];
    __shared__ int hist[512], pfx[512];
    const int tid = threadIdx.x;
    const int range = 1 << shift;
    int cbase = coarseOff[b];
    int cnt = coarseOff[b + 1] - cbase;
    if (cnt > 16384) cnt = 16384;   // safety guard (never expected)
    hist[tid] = 0; hist[tid + 256] = 0;
    __syncthreads();
    for (int i = tid; i < cnt; i += 256) {
        unsigned x = staged[cbase + i];
        rec[i] = x;
        atomicAdd(&hist[x >> 20], 1);
    }
    __syncthreads();
    pfx[tid] = hist[tid]; pfx[tid + 256] = hist[tid + 256];
    __syncthreads();
    for (int dd = 1; dd < 256; dd <<= 1) {
        int a = (tid >= dd) ? pfx[tid - dd] : 0;
        int c = (tid >= dd) ? pfx[tid + 256 - dd] : 0;
        __syncthreads();
        pfx[tid] += a; pfx[tid + 256] += c;
        __syncthreads();
    }
    int tot0 = pfx[255];
    __syncthreads();
    pfx[tid + 256] += tot0;
    __syncthreads();
    int e0 = pfx[tid] - hist[tid];
    int e1 = pfx[tid + 256] - hist[tid + 256];
    __syncthreads();
    hist[tid] = e0; hist[tid + 256] = e1;   // cursors
    int dbase = b << shift;
    if (dbase + tid < N) off[dbase + tid] = cbase + e0;
    if (range > 256 && dbase + tid + 256 < N) off[dbase + tid + 256] = cbase + e1;
    if (b == nb - 1 && tid == 0) off[N] = E;
    __syncthreads();
    for (int i = tid; i < cnt; i += 256) {
        unsigned x = rec[i];
        int p = atomicAdd(&hist[x >> 20], 1);
        staged[cbase + p] = x;
    }
}

// One wave per dst node, both directions. 4 edges per iteration: quarter q
// (16 lanes) reads edge j+q's 128B y-row as uint2 (4 dims/lane). Cross-
// quarter shfl_xor combine at the end; quarter-0 stores hn row as uint2.
__global__ __launch_bounds__(256) void gather_both(
        const int* __restrict__ offI, const int* __restrict__ offU,
        const unsigned* __restrict__ staged1, const unsigned* __restrict__ staged2,
        const uint2* __restrict__ y1, const uint2* __restrict__ y2,
        uint2* __restrict__ hn1, uint2* __restrict__ hn2,
        int NI, int NU) {
    const int lane = threadIdx.x & 63;
    const int qt = lane >> 4;            // quarter 0..3
    const int t  = lane & 15;            // dims 4t..4t+3
    int g = (blockIdx.x * blockDim.x + threadIdx.x) >> 6;
    const bool dirU = g >= NI;
    int n = dirU ? g - NI : g;
    if (dirU && n >= NU) return;
    const int* off = dirU ? offU : offI;
    const unsigned* packed = dirU ? staged2 : staged1;
    const uint2* y = dirU ? y2 : y1;     // row = 16 uint2
    uint2* hn = dirU ? hn2 : hn1;        // row = 16 uint2

    int b = off[n], e = off[n + 1];
    float a0 = 0.f, a1 = 0.f, a2 = 0.f, a3 = 0.f;

#define YROW(mm) y[(((mm) & 0xFFFFFu) << 4) | (unsigned)t]
#define ACC4(dd) { a0 += __uint_as_float((dd).x << 16);          \
                   a1 += __uint_as_float((dd).x & 0xFFFF0000u);  \
                   a2 += __uint_as_float((dd).y << 16);          \
                   a3 += __uint_as_float((dd).y & 0xFFFF0000u); }

    for (int base = b; base < e; base += 64) {
        int idx = base + lane; if (idx > e - 1) idx = e - 1;
        unsigned meta = packed[idx];
        int cnt = e - base; if (cnt > 64) cnt = 64;
        int j = 0;
        for (; j + 4 <= cnt; j += 4) {
            unsigned mm = (unsigned)__shfl((int)meta, j + qt);
            uint2 dd = YROW(mm);
            ACC4(dd);
        }
        int rem = cnt - j;
        if (rem > 0) {
            unsigned mm = (unsigned)__shfl((int)meta, j + qt);  // clamped meta valid
            uint2 dd = YROW(mm);
            if (qt < rem) { ACC4(dd); }
        }
    }
#undef YROW
#undef ACC4

    // combine the 4 quarters (lanes t, t+16, t+32, t+48 hold same dims)
    a0 += __shfl_xor(a0, 16); a1 += __shfl_xor(a1, 16);
    a2 += __shfl_xor(a2, 16); a3 += __shfl_xor(a3, 16);
    a0 += __shfl_xor(a0, 32); a1 += __shfl_xor(a1, 32);
    a2 += __shfl_xor(a2, 32); a3 += __shfl_xor(a3, 32);

    float inv = 1.0f / fmaxf((float)(e - b), 1.0f);
    if (lane < 16) {
        uint2 o;
        o.x = pk2(a0 * inv, a1 * inv);
        o.y = pk2(a2 * inv, a3 * inv);
        hn[(size_t)n * 16 + t] = o;
    }
}

// Per-16-node-tile MFMA transform, both directions:
//   GEMM2 (transposed): h2^T = relu(Wlin @ [hd|hn]^T + blin)
//   GEMM3 (normal):     out  = h2 @ W2^T + b2
__global__ __launch_bounds__(256) void transform_both(
        const unsigned short* __restrict__ hn1, const unsigned short* __restrict__ hn2,
        const unsigned short* __restrict__ hi, const unsigned short* __restrict__ hu,
        const short* __restrict__ pWw, const short* __restrict__ pWwb,
        const float* __restrict__ bw, const float* __restrict__ bwb,
        const short* __restrict__ pVf, const short* __restrict__ pWf,
        const float* __restrict__ bv, const float* __restrict__ bf,
        float* __restrict__ item_out, float* __restrict__ user_out,
        int NI, int NU, int tilesI) {
    const int lane = threadIdx.x & 63;
    const int m = lane & 15, q = lane >> 4;
    int wave = (blockIdx.x * blockDim.x + threadIdx.x) >> 6;
    const bool dirU = wave >= tilesI;
    if (dirU) wave -= tilesI;
    const unsigned short* hn = dirU ? hn2 : hn1;
    const unsigned short* hd = dirU ? hu : hi;
    const short* pWlin = dirU ? pWwb : pWw;
    const float* blin  = dirU ? bwb : bw;
    const short* pW2   = dirU ? pWf : pVf;
    const float* b2    = dirU ? bf : bv;
    float* out = dirU ? user_out : item_out;
    const int N = dirU ? NU : NI;
    const int n0 = wave * 16;
    if (n0 >= N) return;
    int nrow = n0 + m; if (nrow > N - 1) nrow = N - 1;

    bf16x8 bH[2], bHN[2];
    {
        const unsigned short* ph = hd + (size_t)nrow * D + q * 8;
        bH[0] = *(const bf16x8*)(ph);
        bH[1] = *(const bf16x8*)(ph + 32);
        const unsigned short* pn = hn + (size_t)nrow * D + q * 8;
        bHN[0] = *(const bf16x8*)(pn);
        bHN[1] = *(const bf16x8*)(pn + 32);
    }

    f32x4 acc2[4] = {};
    #pragma unroll
    for (int it = 0; it < 4; ++it)
        #pragma unroll
        for (int kt = 0; kt < 4; ++kt) {
            bf16x8 a = *(const bf16x8*)(pWlin + (((it * 4) + kt) << 9) + (lane << 3));
            bf16x8 b = (kt < 2) ? bH[kt] : bHN[kt - 2];
            acc2[it] = __builtin_amdgcn_mfma_f32_16x16x32_bf16(a, b, acc2[it], 0, 0, 0);
        }

    const int srcA = ((q & 1) << 5) + m;
    const int srcB = srcA + 16;
    const bool hiq = (q >> 1) != 0;
    uint32_t u0[4], u1[4];
    float vbl = blin[lane];
    #pragma unroll
    for (int it = 0; it < 4; ++it) {
        float h0 = fmaxf(acc2[it][0] + __shfl(vbl, it * 16 + q * 4 + 0), 0.f);
        float h1 = fmaxf(acc2[it][1] + __shfl(vbl, it * 16 + q * 4 + 1), 0.f);
        float h2 = fmaxf(acc2[it][2] + __shfl(vbl, it * 16 + q * 4 + 2), 0.f);
        float h3 = fmaxf(acc2[it][3] + __shfl(vbl, it * 16 + q * 4 + 3), 0.f);
        u0[it] = pk2(h0, h1);
        u1[it] = pk2(h2, h3);
    }
    bf16x8 bA3[2];
    #pragma unroll
    for (int w = 0; w < 2; ++w) {
        uint32_t aa0 = (uint32_t)__shfl((int)u0[2*w],   srcA), bb0 = (uint32_t)__shfl((int)u0[2*w+1], srcA);
        uint32_t aa1 = (uint32_t)__shfl((int)u1[2*w],   srcA), bb1 = (uint32_t)__shfl((int)u1[2*w+1], srcA);
        uint32_t aa2 = (uint32_t)__shfl((int)u0[2*w],   srcB), bb2 = (uint32_t)__shfl((int)u0[2*w+1], srcB);
        uint32_t aa3 = (uint32_t)__shfl((int)u1[2*w],   srcB), bb3 = (uint32_t)__shfl((int)u1[2*w+1], srcB);
        FragU f;
        f.u[0] = hiq ? bb0 : aa0;
        f.u[1] = hiq ? bb1 : aa1;
        f.u[2] = hiq ? bb2 : aa2;
        f.u[3] = hiq ? bb3 : aa3;
        bA3[w] = f.v;
    }

    f32x4 acc3[4] = {};
    #pragma unroll
    for (int ct = 0; ct < 4; ++ct)
        #pragma unroll
        for (int kt = 0; kt < 2; ++kt) {
            bf16x8 b = *(const bf16x8*)(pW2 + (((ct * 2) + kt) << 9) + (lane << 3));
            acc3[ct] = __builtin_amdgcn_mfma_f32_16x16x32_bf16(bA3[kt], b, acc3[ct], 0, 0, 0);
        }
    #pragma unroll
    for (int ct = 0; ct < 4; ++ct) {
        float bb = b2[ct * 16 + m];
        #pragma unroll
        for (int rg = 0; rg < 4; ++rg) {
            int n = n0 + q * 4 + rg;
            if (n < N) out[(size_t)n * D + ct * 16 + m] = acc3[ct][rg] + bb;
        }
    }
}

extern "C" void kernel_launch(void* const* d_in, const int* in_sizes, int n_in,
                              void* d_out, int out_size, void* d_ws, size_t ws_size,
                              hipStream_t stream) {
    const int*   user_ids   = (const int*)  d_in[0];
    const int*   item_ids   = (const int*)  d_in[1];
    const int*   gender     = (const int*)  d_in[2];
    const int*   genres     = (const int*)  d_in[3];
    const int*   edge_user  = (const int*)  d_in[4];
    const int*   edge_item  = (const int*)  d_in[5];
    const int*   rating     = (const int*)  d_in[6];
    const float* user_emb   = (const float*)d_in[7];
    const float* item_emb   = (const float*)d_in[8];
    const float* gender_emb = (const float*)d_in[9];
    const float* genre_emb  = (const float*)d_in[10];
    const float* Wr_watched   = (const float*)d_in[11];
    const float* Wr_watchedby = (const float*)d_in[12];
    const float* Ww  = (const float*)d_in[13];
    const float* bw  = (const float*)d_in[14];
    const float* Wwb = (const float*)d_in[15];
    const float* bwb = (const float*)d_in[16];
    const float* Wf  = (const float*)d_in[17];
    const float* bf  = (const float*)d_in[18];
    const float* Vf  = (const float*)d_in[19];
    const float* bv  = (const float*)d_in[20];

    const int NU = in_sizes[0];
    const int NI = in_sizes[1];
    const int E  = in_sizes[4];
    const int NBI = (NI + 255) >> 8;   // coarse buckets (shift 8)
    const int NBU = (NU + 511) >> 9;   // coarse buckets (shift 9)

    float* out_f    = (float*)d_out;
    float* user_out = out_f;                       // [NU,64]
    float* item_out = out_f + (size_t)NU * D;      // [NI,64]

    // ws layout (bf16 first): hu, hi, hn1, hn2, y1, y2, packs, ints, staged x2
    unsigned short* hu  = (unsigned short*)d_ws;
    unsigned short* hi  = hu  + (size_t)NU * D;
    unsigned short* hn1 = hi  + (size_t)NI * D;            // items' agg
    unsigned short* hn2 = hn1 + (size_t)NI * D;            // users' agg
    unsigned short* y1  = hn2 + (size_t)NU * D;            // [6][NU][64]
    unsigned short* y2  = y1  + (size_t)NRAT * NU * D;     // [6][NI][64]
    size_t bfElems = (size_t)(2 * NU + 2 * NI) * D + (size_t)NRAT * (NU + NI) * D;
    size_t byteOff = (bfElems * 2 + 15) & ~(size_t)15;
    short* pWrW  = (short*)((char*)d_ws + byteOff);
    short* pWrWB = pWrW  + 24576;
    short* pWw   = pWrWB + 24576;
    short* pWwb  = pWw   + 8192;
    short* pVf   = pWwb  + 8192;
    short* pWf   = pVf   + 4096;
    int* coarseCntI = (int*)(pWf + 4096);   // 256, start of zeroRegion
    int* coarseCntU = coarseCntI + 256;     // 256, end of zeroRegion (512 ints)
    int* coarseOffI = coarseCntU + 256;     // 257
    int* coarseOffU = coarseOffI + 257;     // 257
    int* coarseCurI = coarseOffU + 257;     // 256
    int* coarseCurU = coarseCurI + 256;     // 256
    int* offI   = coarseCurU + 256;         // NI+1
    int* offU   = offI + NI + 1;            // NU+1
    unsigned* staged1 = (unsigned*)(offU + NU + 1);  // E
    unsigned* staged2 = staged1 + E;                 // E

    // 0. zero the coarse counters (2 KB)
    hipMemsetAsync(coarseCntI, 0, 512 * sizeof(int), stream);

    // 1. setup: node features + weight packing + edge histogram (1 dispatch)
    int totalh = (NU + NI) * 16;
    build_setup<<<(totalh + 255) / 256, 256, 0, stream>>>(
        user_ids, item_ids, gender, genres,
        user_emb, item_emb, gender_emb, genre_emb, hu, hi,
        edge_item, edge_user, coarseCntI, coarseCntU, E,
        Wr_watched, Wr_watchedby, Ww, Wwb, Vf, Wf,
        pWrW, pWrWB, pWw, pWwb, pVf, pWf, NU, NI);

    // 2. coarse scan
    scan_both<<<2, 256, 0, stream>>>(coarseCntI, coarseCntU, coarseOffI, coarseOffU,
                                     coarseCurI, coarseCurU, NBI, NBU, E);

    // 3. sort pass A (both dirs, TILE_A) + pretransform (hidden) in one launch
    const int nTilesA = (E + TILE_A - 1) / TILE_A;
    const int wavesU = (NU + 15) / 16, wavesI = (NI + 15) / 16;
    const int ptBlocks = (wavesU + wavesI + 3) / 4;
    msA_pre<<<2 * nTilesA + ptBlocks, 256, 0, stream>>>(
        edge_item, edge_user, rating, coarseCurI, coarseCurU, staged1, staged2,
        hu, hi, pWrW, pWrWB, y1, y2, E, nTilesA, NU, NI, wavesU);

    // 4. sort pass B (both dirs)
    multisplit_B2<<<NBI + NBU, 256, 0, stream>>>(staged1, staged2, coarseOffI, coarseOffU,
                                                 offI, offU, NBI, NU, NI, E);

    // 5. gather both, transform both
    gather_both<<<(NI + NU + 3) / 4, 256, 0, stream>>>(offI, offU, staged1, staged2,
                                                       (const uint2*)y1, (const uint2*)y2,
                                                       (uint2*)hn1, (uint2*)hn2, NI, NU);
    {
        int tilesI = (NI + 15) / 16, tilesU = (NU + 15) / 16;
        int blocks = (tilesI + tilesU + 3) / 4;
        transform_both<<<blocks, 256, 0, stream>>>(hn1, hn2, hi, hu, pWw, pWwb, bw, bwb,
                                                   pVf, pWf, bv, bf, item_out, user_out,
                                                   NI, NU, tilesI);
    }
}

// Round 15
// 200.823 us; speedup vs baseline: 1.3293x; 1.0476x over previous
//
#include <hip/hip_runtime.h>
#include <hip/hip_bf16.h>

#define D 64
#define NRAT 6
#define TILE_A 4096

typedef float f32x4 __attribute__((ext_vector_type(4)));
typedef short bf16x8 __attribute__((ext_vector_type(8)));

union FragU { uint32_t u[4]; bf16x8 v; };

__device__ __forceinline__ short f2bf(float f) {
    __hip_bfloat16 h = __float2bfloat16(f);
    union { __hip_bfloat16 h; short s; } c; c.h = h; return c.s;
}
__device__ __forceinline__ uint32_t pk2(float a, float b) {
    union { short s[2]; uint32_t u; } c; c.s[0] = f2bf(a); c.s[1] = f2bf(b); return c.u;
}

// Fused setup: (a) first 512 blocks also histogram both edge arrays (LDS
// hists, merged by atomics into pre-zeroed cntI/cntU); (b) node features
// hu/hi in bf16; (c) threads [1024,1024+73728) pack weights to MFMA order.
__global__ void build_setup(const int* __restrict__ uid, const int* __restrict__ iid,
                            const int* __restrict__ gender, const int* __restrict__ genres,
                            const float* __restrict__ user_emb, const float* __restrict__ item_emb,
                            const float* __restrict__ gender_emb, const float* __restrict__ genre_emb,
                            unsigned short* __restrict__ hu, unsigned short* __restrict__ hi,
                            const int* __restrict__ edge_item, const int* __restrict__ edge_user,
                            int* __restrict__ cntI, int* __restrict__ cntU, int E,
                            const float* __restrict__ Wr_w, const float* __restrict__ Wr_wb,
                            const float* __restrict__ Ww, const float* __restrict__ Wwb,
                            const float* __restrict__ Vf, const float* __restrict__ Wf,
                            short* __restrict__ pWrW, short* __restrict__ pWrWB,
                            short* __restrict__ pWw, short* __restrict__ pWwb,
                            short* __restrict__ pVf, short* __restrict__ pWf,
                            int NU, int NI) {
    // ---- edge histogram on first 512 blocks (block-uniform branch) ----
    if (blockIdx.x < 512) {
        __shared__ int hI[256], hU[256];
        hI[threadIdx.x] = 0; hU[threadIdx.x] = 0;
        __syncthreads();
        for (int i = blockIdx.x * 256 + threadIdx.x; i < E; i += 512 * 256) {
            atomicAdd(&hI[edge_item[i] >> 8], 1);
            atomicAdd(&hU[edge_user[i] >> 9], 1);
        }
        __syncthreads();
        int vi = hI[threadIdx.x], vu = hU[threadIdx.x];
        if (vi) atomicAdd(&cntI[threadIdx.x], vi);
        if (vu) atomicAdd(&cntU[threadIdx.x], vu);
    }

    int t = blockIdx.x * blockDim.x + threadIdx.x;

    // ---- weight packing on threads [1024, 1024+73728) ----
    int tp = t - 1024;
    if (tp >= 0 && tp < 73728) {
        const float* src; short* dst; int K; int idx;
        if      (tp < 24576) { src = Wr_w;  dst = pWrW;  K = 64;  idx = tp; }
        else if (tp < 49152) { src = Wr_wb; dst = pWrWB; K = 64;  idx = tp - 24576; }
        else if (tp < 57344) { src = Ww;    dst = pWw;   K = 128; idx = tp - 49152; }
        else if (tp < 65536) { src = Wwb;   dst = pWwb;  K = 128; idx = tp - 57344; }
        else if (tp < 69632) { src = Vf;    dst = pVf;   K = 64;  idx = tp - 65536; }
        else                 { src = Wf;    dst = pWf;   K = 64;  idx = tp - 69632; }
        int per  = 64 * K;
        int sub  = idx / per;
        int li   = idx % per;
        int e    = li & 7;
        int lane = (li >> 3) & 63;
        int frag = li >> 9;
        int nkt  = K >> 5;
        int t16  = frag / nkt, tk = frag % nkt;
        int row  = t16 * 16 + (lane & 15);
        int col  = tk * 32 + (lane >> 4) * 8 + e;
        dst[idx] = f2bf(src[((size_t)(sub * 64 + row)) * K + col]);
    }

    // ---- node features ----
    int total = (NU + NI) * 16;          // one float4 (4 dims) per thread
    if (t >= total) return;
    int row = t >> 4, c = t & 15;
    uint2 o;
    if (row < NU) {
        int u = uid[row], g = gender[row];
        float4 a = ((const float4*)user_emb)[(size_t)u * 16 + c];
        float4 b = ((const float4*)gender_emb)[(size_t)g * 16 + c];
        o.x = pk2(a.x + b.x, a.y + b.y); o.y = pk2(a.z + b.z, a.w + b.w);
        ((uint2*)hu)[(size_t)row * 16 + c] = o;
    } else {
        int r2 = row - NU;
        int it = iid[r2], ge = genres[r2];
        float4 a = ((const float4*)item_emb)[(size_t)it * 16 + c];
        float4 b = ((const float4*)genre_emb)[(size_t)ge * 16 + c];
        o.x = pk2(a.x + b.x, a.y + b.y); o.y = pk2(a.z + b.z, a.w + b.w);
        ((uint2*)hi)[(size_t)r2 * 16 + c] = o;
    }
}

// 2 blocks: block 0 scans items' coarse counts, block 1 users'.
__global__ __launch_bounds__(256) void scan_both(const int* __restrict__ cntI,
                                                 const int* __restrict__ cntU,
                                                 int* __restrict__ offI, int* __restrict__ offU,
                                                 int* __restrict__ curI, int* __restrict__ curU,
                                                 int NBI, int NBU, int E) {
    const int* cnt = blockIdx.x ? cntU : cntI;
    int* coarseOff  = blockIdx.x ? offU : offI;
    int* coarseCur  = blockIdx.x ? curU : curI;
    int NB          = blockIdx.x ? NBU : NBI;
    __shared__ int p[256];
    int tid = threadIdx.x;
    int v = (tid < NB) ? cnt[tid] : 0;
    p[tid] = v; __syncthreads();
    for (int dd = 1; dd < 256; dd <<= 1) {
        int a = (tid >= dd) ? p[tid - dd] : 0;
        __syncthreads();
        p[tid] += a;
        __syncthreads();
    }
    int excl = p[tid] - v;
    if (tid < NB) { coarseOff[tid] = excl; coarseCur[tid] = excl; }
    if (tid == 0) coarseOff[NB] = E;
}

// Merged launch: blocks [0, 2*nTiles) run multisplit pass A (both dirs,
// TILE_A=4096 edges/tile); blocks beyond run the per-source pretransform
// y[r][s] = Wr[r] @ h[s] (independent work, hidden under the sort).
__global__ __launch_bounds__(256) void msA_pre(
        const int* __restrict__ edge_item, const int* __restrict__ edge_user,
        const int* __restrict__ rating,
        int* __restrict__ curI, int* __restrict__ curU,
        unsigned* __restrict__ staged1, unsigned* __restrict__ staged2,
        const unsigned short* __restrict__ hu, const unsigned short* __restrict__ hi,
        const short* __restrict__ pWrW, const short* __restrict__ pWrWB,
        unsigned short* __restrict__ y1, unsigned short* __restrict__ y2,
        int E, int nTiles, int NU, int NI, int wavesU) {
    __shared__ unsigned srt[TILE_A];
    __shared__ int sft[TILE_A];
    __shared__ int hist[256], pfx[256], shm[256];
    const int tid = threadIdx.x;

    if ((int)blockIdx.x >= 2 * nTiles) {
        // ---------------- pretransform section ----------------
        const int lane = tid & 63;
        const int m = lane & 15, q = lane >> 4;
        int wave = (((int)blockIdx.x - 2 * nTiles) * 256 + tid) >> 6;
        const bool dirI = wave >= wavesU;
        const unsigned short* h = dirI ? hi : hu;
        const short* pWr = dirI ? pWrWB : pWrW;
        unsigned short* y = dirI ? y2 : y1;
        const int Ns = dirI ? NI : NU;
        if (dirI) wave -= wavesU;
        const int n0 = wave * 16;
        if (n0 >= Ns) return;
        int nrow = n0 + m; if (nrow > Ns - 1) nrow = Ns - 1;

        bf16x8 bB[2];
        {
            const unsigned short* ph = h + (size_t)nrow * D + q * 8;
            bB[0] = *(const bf16x8*)(ph);
            bB[1] = *(const bf16x8*)(ph + 32);
        }
        const int srcA = ((q & 1) << 5) + m;
        const int srcB = srcA + 16;
        const bool hiq = (q >> 1) != 0;

        #pragma unroll
        for (int r = 0; r < NRAT; ++r) {
            f32x4 acc[4] = {};
            #pragma unroll
            for (int it = 0; it < 4; ++it)
                #pragma unroll
                for (int kt = 0; kt < 2; ++kt) {
                    bf16x8 a = *(const bf16x8*)(pWr + (((r * 4 + it) * 2 + kt) << 9) + (lane << 3));
                    acc[it] = __builtin_amdgcn_mfma_f32_16x16x32_bf16(a, bB[kt], acc[it], 0, 0, 0);
                }
            uint32_t u0[4], u1[4];
            #pragma unroll
            for (int it = 0; it < 4; ++it) {
                u0[it] = pk2(acc[it][0], acc[it][1]);
                u1[it] = pk2(acc[it][2], acc[it][3]);
            }
            #pragma unroll
            for (int w = 0; w < 2; ++w) {
                uint32_t aa0 = (uint32_t)__shfl((int)u0[2*w],   srcA), bb0 = (uint32_t)__shfl((int)u0[2*w+1], srcA);
                uint32_t aa1 = (uint32_t)__shfl((int)u1[2*w],   srcA), bb1 = (uint32_t)__shfl((int)u1[2*w+1], srcA);
                uint32_t aa2 = (uint32_t)__shfl((int)u0[2*w],   srcB), bb2 = (uint32_t)__shfl((int)u0[2*w+1], srcB);
                uint32_t aa3 = (uint32_t)__shfl((int)u1[2*w],   srcB), bb3 = (uint32_t)__shfl((int)u1[2*w+1], srcB);
                FragU f;
                f.u[0] = hiq ? bb0 : aa0;
                f.u[1] = hiq ? bb1 : aa1;
                f.u[2] = hiq ? bb2 : aa2;
                f.u[3] = hiq ? bb3 : aa3;
                *(bf16x8*)(y + ((size_t)r * Ns + nrow) * D + w * 32 + q * 8) = f.v;
            }
        }
        return;
    }

    // ---------------- multisplit pass A section ----------------
    const bool dirU = (int)blockIdx.x >= nTiles;
    const int* dst = dirU ? edge_user : edge_item;
    const int* src = dirU ? edge_item : edge_user;
    const int shift = dirU ? 9 : 8;
    const int Ns = dirU ? NI : NU;
    int* coarseCur = dirU ? curU : curI;
    unsigned* staged = dirU ? staged2 : staged1;
    const int tile = (dirU ? (int)blockIdx.x - nTiles : (int)blockIdx.x) * TILE_A;

    int cnt = E - tile; if (cnt > TILE_A) cnt = TILE_A;
    hist[tid] = 0;
    __syncthreads();
    unsigned rec[16]; int bk[16];
    #pragma unroll
    for (int k = 0; k < 16; ++k) {
        int i = tile + k * 256 + tid;
        bk[k] = -1;
        if (i < E) {
            int d = dst[i], s = src[i], r = rating[i];
            bk[k] = d >> shift;
            rec[k] = (unsigned)(s + r * Ns) | ((unsigned)(d & ((1 << shift) - 1)) << 20);
            atomicAdd(&hist[bk[k]], 1);
        }
    }
    __syncthreads();
    pfx[tid] = hist[tid];
    __syncthreads();
    for (int dd = 1; dd < 256; dd <<= 1) {
        int a = (tid >= dd) ? pfx[tid - dd] : 0;
        __syncthreads();
        pfx[tid] += a;
        __syncthreads();
    }
    int h = hist[tid];
    int excl = pfx[tid] - h;
    int gb = 0;
    if (h > 0) gb = atomicAdd(&coarseCur[tid], h);
    shm[tid] = gb - excl;
    __syncthreads();
    hist[tid] = excl;          // reuse as local cursor
    __syncthreads();
    #pragma unroll
    for (int k = 0; k < 16; ++k) {
        if (bk[k] >= 0) {
            int p = atomicAdd(&hist[bk[k]], 1);
            srt[p] = rec[k];
            sft[p] = shm[bk[k]];
        }
    }
    __syncthreads();
    for (int i = tid; i < cnt; i += 256)
        staged[sft[i] + i] = srt[i];
}

// Pass B, both directions: one block per coarse bucket.
__global__ __launch_bounds__(256) void multisplit_B2(
        unsigned* __restrict__ staged1, unsigned* __restrict__ staged2,
        const int* __restrict__ coarseOffI, const int* __restrict__ coarseOffU,
        int* __restrict__ offI, int* __restrict__ offU,
        int NBI, int NU, int NI, int E) {
    const bool dirU = (int)blockIdx.x >= NBI;
    unsigned* staged = dirU ? staged2 : staged1;
    const int* coarseOff = dirU ? coarseOffU : coarseOffI;
    int* off = dirU ? offU : offI;
    const int N = dirU ? NU : NI;
    const int shift = dirU ? 9 : 8;
    const int b = dirU ? blockIdx.x - NBI : blockIdx.x;
    const int nb = dirU ? (N + (1 << 9) - 1) >> 9 : NBI;

    __shared__ unsigned rec[16384];
    __shared__ int hist[512], pfx[512];
    const int tid = threadIdx.x;
    const int range = 1 << shift;
    int cbase = coarseOff[b];
    int cnt = coarseOff[b + 1] - cbase;
    if (cnt > 16384) cnt = 16384;   // safety guard (never expected)
    hist[tid] = 0; hist[tid + 256] = 0;
    __syncthreads();
    for (int i = tid; i < cnt; i += 256) {
        unsigned x = staged[cbase + i];
        rec[i] = x;
        atomicAdd(&hist[x >> 20], 1);
    }
    __syncthreads();
    pfx[tid] = hist[tid]; pfx[tid + 256] = hist[tid + 256];
    __syncthreads();
    for (int dd = 1; dd < 256; dd <<= 1) {
        int a = (tid >= dd) ? pfx[tid - dd] : 0;
        int c = (tid >= dd) ? pfx[tid + 256 - dd] : 0;
        __syncthreads();
        pfx[tid] += a; pfx[tid + 256] += c;
        __syncthreads();
    }
    int tot0 = pfx[255];
    __syncthreads();
    pfx[tid + 256] += tot0;
    __syncthreads();
    int e0 = pfx[tid] - hist[tid];
    int e1 = pfx[tid + 256] - hist[tid + 256];
    __syncthreads();
    hist[tid] = e0; hist[tid + 256] = e1;   // cursors
    int dbase = b << shift;
    if (dbase + tid < N) off[dbase + tid] = cbase + e0;
    if (range > 256 && dbase + tid + 256 < N) off[dbase + tid + 256] = cbase + e1;
    if (b == nb - 1 && tid == 0) off[N] = E;
    __syncthreads();
    for (int i = tid; i < cnt; i += 256) {
        unsigned x = rec[i];
        int p = atomicAdd(&hist[x >> 20], 1);
        staged[cbase + p] = x;
    }
}

// One wave per dst node, both directions. 8 edges per iteration (2-deep
// unroll of the quarter-wave scheme): quarter q reads edges j+q and j+4+q's
// 128B y-rows as uint2 — both loads issued before either ACC chain, doubling
// per-wave MLP. Cross-quarter shfl_xor combine; quarter-0 stores hn.
__global__ __launch_bounds__(256) void gather_both(
        const int* __restrict__ offI, const int* __restrict__ offU,
        const unsigned* __restrict__ staged1, const unsigned* __restrict__ staged2,
        const uint2* __restrict__ y1, const uint2* __restrict__ y2,
        uint2* __restrict__ hn1, uint2* __restrict__ hn2,
        int NI, int NU) {
    const int lane = threadIdx.x & 63;
    const int qt = lane >> 4;            // quarter 0..3
    const int t  = lane & 15;            // dims 4t..4t+3
    int g = (blockIdx.x * blockDim.x + threadIdx.x) >> 6;
    const bool dirU = g >= NI;
    int n = dirU ? g - NI : g;
    if (dirU && n >= NU) return;
    const int* off = dirU ? offU : offI;
    const unsigned* packed = dirU ? staged2 : staged1;
    const uint2* y = dirU ? y2 : y1;     // row = 16 uint2
    uint2* hn = dirU ? hn2 : hn1;        // row = 16 uint2

    int b = off[n], e = off[n + 1];
    float a0 = 0.f, a1 = 0.f, a2 = 0.f, a3 = 0.f;

#define YROW(mm) y[(((mm) & 0xFFFFFu) << 4) | (unsigned)t]
#define ACC4(dd) { a0 += __uint_as_float((dd).x << 16);          \
                   a1 += __uint_as_float((dd).x & 0xFFFF0000u);  \
                   a2 += __uint_as_float((dd).y << 16);          \
                   a3 += __uint_as_float((dd).y & 0xFFFF0000u); }

    for (int base = b; base < e; base += 64) {
        int idx = base + lane; if (idx > e - 1) idx = e - 1;
        unsigned meta = packed[idx];
        int cnt = e - base; if (cnt > 64) cnt = 64;
        int j = 0;
        for (; j + 8 <= cnt; j += 8) {
            unsigned mA = (unsigned)__shfl((int)meta, j + qt);
            unsigned mB = (unsigned)__shfl((int)meta, j + 4 + qt);
            uint2 dA = YROW(mA);
            uint2 dB = YROW(mB);
            ACC4(dA);
            ACC4(dB);
        }
        if (j + 4 <= cnt) {
            unsigned mm = (unsigned)__shfl((int)meta, j + qt);
            uint2 dd = YROW(mm);
            ACC4(dd);
            j += 4;
        }
        int rem = cnt - j;
        if (rem > 0) {
            unsigned mm = (unsigned)__shfl((int)meta, j + qt);  // clamped meta valid
            uint2 dd = YROW(mm);
            if (qt < rem) { ACC4(dd); }
        }
    }
#undef YROW
#undef ACC4

    // combine the 4 quarters (lanes t, t+16, t+32, t+48 hold same dims)
    a0 += __shfl_xor(a0, 16); a1 += __shfl_xor(a1, 16);
    a2 += __shfl_xor(a2, 16); a3 += __shfl_xor(a3, 16);
    a0 += __shfl_xor(a0, 32); a1 += __shfl_xor(a1, 32);
    a2 += __shfl_xor(a2, 32); a3 += __shfl_xor(a3, 32);

    float inv = 1.0f / fmaxf((float)(e - b), 1.0f);
    if (lane < 16) {
        uint2 o;
        o.x = pk2(a0 * inv, a1 * inv);
        o.y = pk2(a2 * inv, a3 * inv);
        hn[(size_t)n * 16 + t] = o;
    }
}

// Per-16-node-tile MFMA transform, both directions:
//   GEMM2 (transposed): h2^T = relu(Wlin @ [hd|hn]^T + blin)
//   GEMM3 (normal):     out  = h2 @ W2^T + b2
__global__ __launch_bounds__(256) void transform_both(
        const unsigned short* __restrict__ hn1, const unsigned short* __restrict__ hn2,
        const unsigned short* __restrict__ hi, const unsigned short* __restrict__ hu,
        const short* __restrict__ pWw, const short* __restrict__ pWwb,
        const float* __restrict__ bw, const float* __restrict__ bwb,
        const short* __restrict__ pVf, const short* __restrict__ pWf,
        const float* __restrict__ bv, const float* __restrict__ bf,
        float* __restrict__ item_out, float* __restrict__ user_out,
        int NI, int NU, int tilesI) {
    const int lane = threadIdx.x & 63;
    const int m = lane & 15, q = lane >> 4;
    int wave = (blockIdx.x * blockDim.x + threadIdx.x) >> 6;
    const bool dirU = wave >= tilesI;
    if (dirU) wave -= tilesI;
    const unsigned short* hn = dirU ? hn2 : hn1;
    const unsigned short* hd = dirU ? hu : hi;
    const short* pWlin = dirU ? pWwb : pWw;
    const float* blin  = dirU ? bwb : bw;
    const short* pW2   = dirU ? pWf : pVf;
    const float* b2    = dirU ? bf : bv;
    float* out = dirU ? user_out : item_out;
    const int N = dirU ? NU : NI;
    const int n0 = wave * 16;
    if (n0 >= N) return;
    int nrow = n0 + m; if (nrow > N - 1) nrow = N - 1;

    bf16x8 bH[2], bHN[2];
    {
        const unsigned short* ph = hd + (size_t)nrow * D + q * 8;
        bH[0] = *(const bf16x8*)(ph);
        bH[1] = *(const bf16x8*)(ph + 32);
        const unsigned short* pn = hn + (size_t)nrow * D + q * 8;
        bHN[0] = *(const bf16x8*)(pn);
        bHN[1] = *(const bf16x8*)(pn + 32);
    }

    f32x4 acc2[4] = {};
    #pragma unroll
    for (int it = 0; it < 4; ++it)
        #pragma unroll
        for (int kt = 0; kt < 4; ++kt) {
            bf16x8 a = *(const bf16x8*)(pWlin + (((it * 4) + kt) << 9) + (lane << 3));
            bf16x8 b = (kt < 2) ? bH[kt] : bHN[kt - 2];
            acc2[it] = __builtin_amdgcn_mfma_f32_16x16x32_bf16(a, b, acc2[it], 0, 0, 0);
        }

    const int srcA = ((q & 1) << 5) + m;
    const int srcB = srcA + 16;
    const bool hiq = (q >> 1) != 0;
    uint32_t u0[4], u1[4];
    float vbl = blin[lane];
    #pragma unroll
    for (int it = 0; it < 4; ++it) {
        float h0 = fmaxf(acc2[it][0] + __shfl(vbl, it * 16 + q * 4 + 0), 0.f);
        float h1 = fmaxf(acc2[it][1] + __shfl(vbl, it * 16 + q * 4 + 1), 0.f);
        float h2 = fmaxf(acc2[it][2] + __shfl(vbl, it * 16 + q * 4 + 2), 0.f);
        float h3 = fmaxf(acc2[it][3] + __shfl(vbl, it * 16 + q * 4 + 3), 0.f);
        u0[it] = pk2(h0, h1);
        u1[it] = pk2(h2, h3);
    }
    bf16x8 bA3[2];
    #pragma unroll
    for (int w = 0; w < 2; ++w) {
        uint32_t aa0 = (uint32_t)__shfl((int)u0[2*w],   srcA), bb0 = (uint32_t)__shfl((int)u0[2*w+1], srcA);
        uint32_t aa1 = (uint32_t)__shfl((int)u1[2*w],   srcA), bb1 = (uint32_t)__shfl((int)u1[2*w+1], srcA);
        uint32_t aa2 = (uint32_t)__shfl((int)u0[2*w],   srcB), bb2 = (uint32_t)__shfl((int)u0[2*w+1], srcB);
        uint32_t aa3 = (uint32_t)__shfl((int)u1[2*w],   srcB), bb3 = (uint32_t)__shfl((int)u1[2*w+1], srcB);
        FragU f;
        f.u[0] = hiq ? bb0 : aa0;
        f.u[1] = hiq ? bb1 : aa1;
        f.u[2] = hiq ? bb2 : aa2;
        f.u[3] = hiq ? bb3 : aa3;
        bA3[w] = f.v;
    }

    f32x4 acc3[4] = {};
    #pragma unroll
    for (int ct = 0; ct < 4; ++ct)
        #pragma unroll
        for (int kt = 0; kt < 2; ++kt) {
            bf16x8 b = *(const bf16x8*)(pW2 + (((ct * 2) + kt) << 9) + (lane << 3));
            acc3[ct] = __builtin_amdgcn_mfma_f32_16x16x32_bf16(bA3[kt], b, acc3[ct], 0, 0, 0);
        }
    #pragma unroll
    for (int ct = 0; ct < 4; ++ct) {
        float bb = b2[ct * 16 + m];
        #pragma unroll
        for (int rg = 0; rg < 4; ++rg) {
            int n = n0 + q * 4 + rg;
            if (n < N) out[(size_t)n * D + ct * 16 + m] = acc3[ct][rg] + bb;
        }
    }
}

extern "C" void kernel_launch(void* const* d_in, const int* in_sizes, int n_in,
                              void* d_out, int out_size, void* d_ws, size_t ws_size,
                              hipStream_t stream) {
    const int*   user_ids   = (const int*)  d_in[0];
    const int*   item_ids   = (const int*)  d_in[1];
    const int*   gender     = (const int*)  d_in[2];
    const int*   genres     = (const int*)  d_in[3];
    const int*   edge_user  = (const int*)  d_in[4];
    const int*   edge_item  = (const int*)  d_in[5];
    const int*   rating     = (const int*)  d_in[6];
    const float* user_emb   = (const float*)d_in[7];
    const float* item_emb   = (const float*)d_in[8];
    const float* gender_emb = (const float*)d_in[9];
    const float* genre_emb  = (const float*)d_in[10];
    const float* Wr_watched   = (const float*)d_in[11];
    const float* Wr_watchedby = (const float*)d_in[12];
    const float* Ww  = (const float*)d_in[13];
    const float* bw  = (const float*)d_in[14];
    const float* Wwb = (const float*)d_in[15];
    const float* bwb = (const float*)d_in[16];
    const float* Wf  = (const float*)d_in[17];
    const float* bf  = (const float*)d_in[18];
    const float* Vf  = (const float*)d_in[19];
    const float* bv  = (const float*)d_in[20];

    const int NU = in_sizes[0];
    const int NI = in_sizes[1];
    const int E  = in_sizes[4];
    const int NBI = (NI + 255) >> 8;   // coarse buckets (shift 8)
    const int NBU = (NU + 511) >> 9;   // coarse buckets (shift 9)

    float* out_f    = (float*)d_out;
    float* user_out = out_f;                       // [NU,64]
    float* item_out = out_f + (size_t)NU * D;      // [NI,64]

    // ws layout (bf16 first): hu, hi, hn1, hn2, y1, y2, packs, ints, staged x2
    unsigned short* hu  = (unsigned short*)d_ws;
    unsigned short* hi  = hu  + (size_t)NU * D;
    unsigned short* hn1 = hi  + (size_t)NI * D;            // items' agg
    unsigned short* hn2 = hn1 + (size_t)NI * D;            // users' agg
    unsigned short* y1  = hn2 + (size_t)NU * D;            // [6][NU][64]
    unsigned short* y2  = y1  + (size_t)NRAT * NU * D;     // [6][NI][64]
    size_t bfElems = (size_t)(2 * NU + 2 * NI) * D + (size_t)NRAT * (NU + NI) * D;
    size_t byteOff = (bfElems * 2 + 15) & ~(size_t)15;
    short* pWrW  = (short*)((char*)d_ws + byteOff);
    short* pWrWB = pWrW  + 24576;
    short* pWw   = pWrWB + 24576;
    short* pWwb  = pWw   + 8192;
    short* pVf   = pWwb  + 8192;
    short* pWf   = pVf   + 4096;
    int* coarseCntI = (int*)(pWf + 4096);   // 256, start of zeroRegion
    int* coarseCntU = coarseCntI + 256;     // 256, end of zeroRegion (512 ints)
    int* coarseOffI = coarseCntU + 256;     // 257
    int* coarseOffU = coarseOffI + 257;     // 257
    int* coarseCurI = coarseOffU + 257;     // 256
    int* coarseCurU = coarseCurI + 256;     // 256
    int* offI   = coarseCurU + 256;         // NI+1
    int* offU   = offI + NI + 1;            // NU+1
    unsigned* staged1 = (unsigned*)(offU + NU + 1);  // E
    unsigned* staged2 = staged1 + E;                 // E

    // 0. zero the coarse counters (2 KB)
    hipMemsetAsync(coarseCntI, 0, 512 * sizeof(int), stream);

    // 1. setup: node features + weight packing + edge histogram (1 dispatch)
    int totalh = (NU + NI) * 16;
    build_setup<<<(totalh + 255) / 256, 256, 0, stream>>>(
        user_ids, item_ids, gender, genres,
        user_emb, item_emb, gender_emb, genre_emb, hu, hi,
        edge_item, edge_user, coarseCntI, coarseCntU, E,
        Wr_watched, Wr_watchedby, Ww, Wwb, Vf, Wf,
        pWrW, pWrWB, pWw, pWwb, pVf, pWf, NU, NI);

    // 2. coarse scan
    scan_both<<<2, 256, 0, stream>>>(coarseCntI, coarseCntU, coarseOffI, coarseOffU,
                                     coarseCurI, coarseCurU, NBI, NBU, E);

    // 3. sort pass A (both dirs, TILE_A) + pretransform (hidden) in one launch
    const int nTilesA = (E + TILE_A - 1) / TILE_A;
    const int wavesU = (NU + 15) / 16, wavesI = (NI + 15) / 16;
    const int ptBlocks = (wavesU + wavesI + 3) / 4;
    msA_pre<<<2 * nTilesA + ptBlocks, 256, 0, stream>>>(
        edge_item, edge_user, rating, coarseCurI, coarseCurU, staged1, staged2,
        hu, hi, pWrW, pWrWB, y1, y2, E, nTilesA, NU, NI, wavesU);

    // 4. sort pass B (both dirs)
    multisplit_B2<<<NBI + NBU, 256, 0, stream>>>(staged1, staged2, coarseOffI, coarseOffU,
                                                 offI, offU, NBI, NU, NI, E);

    // 5. gather both, transform both
    gather_both<<<(NI + NU + 3) / 4, 256, 0, stream>>>(offI, offU, staged1, staged2,
                                                       (const uint2*)y1, (const uint2*)y2,
                                                       (uint2*)hn1, (uint2*)hn2, NI, NU);
    {
        int tilesI = (NI + 15) / 16, tilesU = (NU + 15) / 16;
        int blocks = (tilesI + tilesU + 3) / 4;
        transform_both<<<blocks, 256, 0, stream>>>(hn1, hn2, hi, hu, pWw, pWwb, bw, bwb,
                                                   pVf, pWf, bv, bf, item_out, user_out,
                                                   NI, NU, tilesI);
    }
}

// Round 16
// 195.787 us; speedup vs baseline: 1.3635x; 1.0257x over previous
//
#include <hip/hip_runtime.h>
#include <hip/hip_bf16.h>

#define D 64
#define NRAT 6
#define TILE_A 4096

typedef float f32x4 __attribute__((ext_vector_type(4)));
typedef short bf16x8 __attribute__((ext_vector_type(8)));

union FragU { uint32_t u[4]; bf16x8 v; };

__device__ __forceinline__ short f2bf(float f) {
    __hip_bfloat16 h = __float2bfloat16(f);
    union { __hip_bfloat16 h; short s; } c; c.h = h; return c.s;
}
__device__ __forceinline__ uint32_t pk2(float a, float b) {
    union { short s[2]; uint32_t u; } c; c.s[0] = f2bf(a); c.s[1] = f2bf(b); return c.u;
}

// Fused setup: (a) first 512 blocks also histogram both edge arrays (LDS
// hists, merged by atomics into pre-zeroed cntI/cntU); (b) node features
// hu/hi in bf16; (c) threads [1024,1024+73728) pack weights to MFMA order.
__global__ void build_setup(const int* __restrict__ uid, const int* __restrict__ iid,
                            const int* __restrict__ gender, const int* __restrict__ genres,
                            const float* __restrict__ user_emb, const float* __restrict__ item_emb,
                            const float* __restrict__ gender_emb, const float* __restrict__ genre_emb,
                            unsigned short* __restrict__ hu, unsigned short* __restrict__ hi,
                            const int* __restrict__ edge_item, const int* __restrict__ edge_user,
                            int* __restrict__ cntI, int* __restrict__ cntU, int E,
                            const float* __restrict__ Wr_w, const float* __restrict__ Wr_wb,
                            const float* __restrict__ Ww, const float* __restrict__ Wwb,
                            const float* __restrict__ Vf, const float* __restrict__ Wf,
                            short* __restrict__ pWrW, short* __restrict__ pWrWB,
                            short* __restrict__ pWw, short* __restrict__ pWwb,
                            short* __restrict__ pVf, short* __restrict__ pWf,
                            int NU, int NI) {
    // ---- edge histogram on first 512 blocks (block-uniform branch) ----
    if (blockIdx.x < 512) {
        __shared__ int hI[256], hU[256];
        hI[threadIdx.x] = 0; hU[threadIdx.x] = 0;
        __syncthreads();
        for (int i = blockIdx.x * 256 + threadIdx.x; i < E; i += 512 * 256) {
            atomicAdd(&hI[edge_item[i] >> 8], 1);
            atomicAdd(&hU[edge_user[i] >> 9], 1);
        }
        __syncthreads();
        int vi = hI[threadIdx.x], vu = hU[threadIdx.x];
        if (vi) atomicAdd(&cntI[threadIdx.x], vi);
        if (vu) atomicAdd(&cntU[threadIdx.x], vu);
    }

    int t = blockIdx.x * blockDim.x + threadIdx.x;

    // ---- weight packing on threads [1024, 1024+73728) ----
    int tp = t - 1024;
    if (tp >= 0 && tp < 73728) {
        const float* src; short* dst; int K; int idx;
        if      (tp < 24576) { src = Wr_w;  dst = pWrW;  K = 64;  idx = tp; }
        else if (tp < 49152) { src = Wr_wb; dst = pWrWB; K = 64;  idx = tp - 24576; }
        else if (tp < 57344) { src = Ww;    dst = pWw;   K = 128; idx = tp - 49152; }
        else if (tp < 65536) { src = Wwb;   dst = pWwb;  K = 128; idx = tp - 57344; }
        else if (tp < 69632) { src = Vf;    dst = pVf;   K = 64;  idx = tp - 65536; }
        else                 { src = Wf;    dst = pWf;   K = 64;  idx = tp - 69632; }
        int per  = 64 * K;
        int sub  = idx / per;
        int li   = idx % per;
        int e    = li & 7;
        int lane = (li >> 3) & 63;
        int frag = li >> 9;
        int nkt  = K >> 5;
        int t16  = frag / nkt, tk = frag % nkt;
        int row  = t16 * 16 + (lane & 15);
        int col  = tk * 32 + (lane >> 4) * 8 + e;
        dst[idx] = f2bf(src[((size_t)(sub * 64 + row)) * K + col]);
    }

    // ---- node features ----
    int total = (NU + NI) * 16;          // one float4 (4 dims) per thread
    if (t >= total) return;
    int row = t >> 4, c = t & 15;
    uint2 o;
    if (row < NU) {
        int u = uid[row], g = gender[row];
        float4 a = ((const float4*)user_emb)[(size_t)u * 16 + c];
        float4 b = ((const float4*)gender_emb)[(size_t)g * 16 + c];
        o.x = pk2(a.x + b.x, a.y + b.y); o.y = pk2(a.z + b.z, a.w + b.w);
        ((uint2*)hu)[(size_t)row * 16 + c] = o;
    } else {
        int r2 = row - NU;
        int it = iid[r2], ge = genres[r2];
        float4 a = ((const float4*)item_emb)[(size_t)it * 16 + c];
        float4 b = ((const float4*)genre_emb)[(size_t)ge * 16 + c];
        o.x = pk2(a.x + b.x, a.y + b.y); o.y = pk2(a.z + b.z, a.w + b.w);
        ((uint2*)hi)[(size_t)r2 * 16 + c] = o;
    }
}

// 2 blocks: block 0 scans items' coarse counts, block 1 users'.
__global__ __launch_bounds__(256) void scan_both(const int* __restrict__ cntI,
                                                 const int* __restrict__ cntU,
                                                 int* __restrict__ offI, int* __restrict__ offU,
                                                 int* __restrict__ curI, int* __restrict__ curU,
                                                 int NBI, int NBU, int E) {
    const int* cnt = blockIdx.x ? cntU : cntI;
    int* coarseOff  = blockIdx.x ? offU : offI;
    int* coarseCur  = blockIdx.x ? curU : curI;
    int NB          = blockIdx.x ? NBU : NBI;
    __shared__ int p[256];
    int tid = threadIdx.x;
    int v = (tid < NB) ? cnt[tid] : 0;
    p[tid] = v; __syncthreads();
    for (int dd = 1; dd < 256; dd <<= 1) {
        int a = (tid >= dd) ? p[tid - dd] : 0;
        __syncthreads();
        p[tid] += a;
        __syncthreads();
    }
    int excl = p[tid] - v;
    if (tid < NB) { coarseOff[tid] = excl; coarseCur[tid] = excl; }
    if (tid == 0) coarseOff[NB] = E;
}

// Merged launch: blocks [0, 2*nTiles) run multisplit pass A (both dirs,
// TILE_A=4096 edges/tile); blocks beyond run the per-source pretransform
// y[r][s] = Wr[r] @ h[s] (independent work, hidden under the sort).
__global__ __launch_bounds__(256) void msA_pre(
        const int* __restrict__ edge_item, const int* __restrict__ edge_user,
        const int* __restrict__ rating,
        int* __restrict__ curI, int* __restrict__ curU,
        unsigned* __restrict__ staged1, unsigned* __restrict__ staged2,
        const unsigned short* __restrict__ hu, const unsigned short* __restrict__ hi,
        const short* __restrict__ pWrW, const short* __restrict__ pWrWB,
        unsigned short* __restrict__ y1, unsigned short* __restrict__ y2,
        int E, int nTiles, int NU, int NI, int wavesU) {
    __shared__ unsigned srt[TILE_A];
    __shared__ int sft[TILE_A];
    __shared__ int hist[256], pfx[256], shm[256];
    const int tid = threadIdx.x;

    if ((int)blockIdx.x >= 2 * nTiles) {
        // ---------------- pretransform section ----------------
        const int lane = tid & 63;
        const int m = lane & 15, q = lane >> 4;
        int wave = (((int)blockIdx.x - 2 * nTiles) * 256 + tid) >> 6;
        const bool dirI = wave >= wavesU;
        const unsigned short* h = dirI ? hi : hu;
        const short* pWr = dirI ? pWrWB : pWrW;
        unsigned short* y = dirI ? y2 : y1;
        const int Ns = dirI ? NI : NU;
        if (dirI) wave -= wavesU;
        const int n0 = wave * 16;
        if (n0 >= Ns) return;
        int nrow = n0 + m; if (nrow > Ns - 1) nrow = Ns - 1;

        bf16x8 bB[2];
        {
            const unsigned short* ph = h + (size_t)nrow * D + q * 8;
            bB[0] = *(const bf16x8*)(ph);
            bB[1] = *(const bf16x8*)(ph + 32);
        }
        const int srcA = ((q & 1) << 5) + m;
        const int srcB = srcA + 16;
        const bool hiq = (q >> 1) != 0;

        #pragma unroll
        for (int r = 0; r < NRAT; ++r) {
            f32x4 acc[4] = {};
            #pragma unroll
            for (int it = 0; it < 4; ++it)
                #pragma unroll
                for (int kt = 0; kt < 2; ++kt) {
                    bf16x8 a = *(const bf16x8*)(pWr + (((r * 4 + it) * 2 + kt) << 9) + (lane << 3));
                    acc[it] = __builtin_amdgcn_mfma_f32_16x16x32_bf16(a, bB[kt], acc[it], 0, 0, 0);
                }
            uint32_t u0[4], u1[4];
            #pragma unroll
            for (int it = 0; it < 4; ++it) {
                u0[it] = pk2(acc[it][0], acc[it][1]);
                u1[it] = pk2(acc[it][2], acc[it][3]);
            }
            #pragma unroll
            for (int w = 0; w < 2; ++w) {
                uint32_t aa0 = (uint32_t)__shfl((int)u0[2*w],   srcA), bb0 = (uint32_t)__shfl((int)u0[2*w+1], srcA);
                uint32_t aa1 = (uint32_t)__shfl((int)u1[2*w],   srcA), bb1 = (uint32_t)__shfl((int)u1[2*w+1], srcA);
                uint32_t aa2 = (uint32_t)__shfl((int)u0[2*w],   srcB), bb2 = (uint32_t)__shfl((int)u0[2*w+1], srcB);
                uint32_t aa3 = (uint32_t)__shfl((int)u1[2*w],   srcB), bb3 = (uint32_t)__shfl((int)u1[2*w+1], srcB);
                FragU f;
                f.u[0] = hiq ? bb0 : aa0;
                f.u[1] = hiq ? bb1 : aa1;
                f.u[2] = hiq ? bb2 : aa2;
                f.u[3] = hiq ? bb3 : aa3;
                *(bf16x8*)(y + ((size_t)r * Ns + nrow) * D + w * 32 + q * 8) = f.v;
            }
        }
        return;
    }

    // ---------------- multisplit pass A section ----------------
    const bool dirU = (int)blockIdx.x >= nTiles;
    const int* dst = dirU ? edge_user : edge_item;
    const int* src = dirU ? edge_item : edge_user;
    const int shift = dirU ? 9 : 8;
    const int Ns = dirU ? NI : NU;
    int* coarseCur = dirU ? curU : curI;
    unsigned* staged = dirU ? staged2 : staged1;
    const int tile = (dirU ? (int)blockIdx.x - nTiles : (int)blockIdx.x) * TILE_A;

    int cnt = E - tile; if (cnt > TILE_A) cnt = TILE_A;
    hist[tid] = 0;
    __syncthreads();
    unsigned rec[16]; int bk[16];
    #pragma unroll
    for (int k = 0; k < 16; ++k) {
        int i = tile + k * 256 + tid;
        bk[k] = -1;
        if (i < E) {
            int d = dst[i], s = src[i], r = rating[i];
            bk[k] = d >> shift;
            rec[k] = (unsigned)(s + r * Ns) | ((unsigned)(d & ((1 << shift) - 1)) << 20);
            atomicAdd(&hist[bk[k]], 1);
        }
    }
    __syncthreads();
    pfx[tid] = hist[tid];
    __syncthreads();
    for (int dd = 1; dd < 256; dd <<= 1) {
        int a = (tid >= dd) ? pfx[tid - dd] : 0;
        __syncthreads();
        pfx[tid] += a;
        __syncthreads();
    }
    int h = hist[tid];
    int excl = pfx[tid] - h;
    int gb = 0;
    if (h > 0) gb = atomicAdd(&coarseCur[tid], h);
    shm[tid] = gb - excl;
    __syncthreads();
    hist[tid] = excl;          // reuse as local cursor
    __syncthreads();
    #pragma unroll
    for (int k = 0; k < 16; ++k) {
        if (bk[k] >= 0) {
            int p = atomicAdd(&hist[bk[k]], 1);
            srt[p] = rec[k];
            sft[p] = shm[bk[k]];
        }
    }
    __syncthreads();
    for (int i = tid; i < cnt; i += 256)
        staged[sft[i] + i] = srt[i];
}

// Pass B, both directions: one block per coarse bucket.
__global__ __launch_bounds__(256) void multisplit_B2(
        unsigned* __restrict__ staged1, unsigned* __restrict__ staged2,
        const int* __restrict__ coarseOffI, const int* __restrict__ coarseOffU,
        int* __restrict__ offI, int* __restrict__ offU,
        int NBI, int NU, int NI, int E) {
    const bool dirU = (int)blockIdx.x >= NBI;
    unsigned* staged = dirU ? staged2 : staged1;
    const int* coarseOff = dirU ? coarseOffU : coarseOffI;
    int* off = dirU ? offU : offI;
    const int N = dirU ? NU : NI;
    const int shift = dirU ? 9 : 8;
    const int b = dirU ? blockIdx.x - NBI : blockIdx.x;
    const int nb = dirU ? (N + (1 << 9) - 1) >> 9 : NBI;

    __shared__ unsigned rec[16384];
    __shared__ int hist[512], pfx[512];
    const int tid = threadIdx.x;
    const int range = 1 << shift;
    int cbase = coarseOff[b];
    int cnt = coarseOff[b + 1] - cbase;
    if (cnt > 16384) cnt = 16384;   // safety guard (never expected)
    hist[tid] = 0; hist[tid + 256] = 0;
    __syncthreads();
    for (int i = tid; i < cnt; i += 256) {
        unsigned x = staged[cbase + i];
        rec[i] = x;
        atomicAdd(&hist[x >> 20], 1);
    }
    __syncthreads();
    pfx[tid] = hist[tid]; pfx[tid + 256] = hist[tid + 256];
    __syncthreads();
    for (int dd = 1; dd < 256; dd <<= 1) {
        int a = (tid >= dd) ? pfx[tid - dd] : 0;
        int c = (tid >= dd) ? pfx[tid + 256 - dd] : 0;
        __syncthreads();
        pfx[tid] += a; pfx[tid + 256] += c;
        __syncthreads();
    }
    int tot0 = pfx[255];
    __syncthreads();
    pfx[tid + 256] += tot0;
    __syncthreads();
    int e0 = pfx[tid] - hist[tid];
    int e1 = pfx[tid + 256] - hist[tid + 256];
    __syncthreads();
    hist[tid] = e0; hist[tid + 256] = e1;   // cursors
    int dbase = b << shift;
    if (dbase + tid < N) off[dbase + tid] = cbase + e0;
    if (range > 256 && dbase + tid + 256 < N) off[dbase + tid + 256] = cbase + e1;
    if (b == nb - 1 && tid == 0) off[N] = E;
    __syncthreads();
    for (int i = tid; i < cnt; i += 256) {
        unsigned x = rec[i];
        int p = atomicAdd(&hist[x >> 20], 1);
        staged[cbase + p] = x;
    }
}

// One wave per dst node, both directions. 16 edges per iteration (4-deep
// unroll of the quarter-wave scheme): quarter q reads edges j+q, j+4+q,
// j+8+q, j+12+q — all 4 uint2 loads issued before any ACC chain (4x MLP).
// Cross-quarter shfl_xor combine; quarter-0 stores hn.
__global__ __launch_bounds__(256) void gather_both(
        const int* __restrict__ offI, const int* __restrict__ offU,
        const unsigned* __restrict__ staged1, const unsigned* __restrict__ staged2,
        const uint2* __restrict__ y1, const uint2* __restrict__ y2,
        uint2* __restrict__ hn1, uint2* __restrict__ hn2,
        int NI, int NU) {
    const int lane = threadIdx.x & 63;
    const int qt = lane >> 4;            // quarter 0..3
    const int t  = lane & 15;            // dims 4t..4t+3
    int g = (blockIdx.x * blockDim.x + threadIdx.x) >> 6;
    const bool dirU = g >= NI;
    int n = dirU ? g - NI : g;
    if (dirU && n >= NU) return;
    const int* off = dirU ? offU : offI;
    const unsigned* packed = dirU ? staged2 : staged1;
    const uint2* y = dirU ? y2 : y1;     // row = 16 uint2
    uint2* hn = dirU ? hn2 : hn1;        // row = 16 uint2

    int b = off[n], e = off[n + 1];
    float a0 = 0.f, a1 = 0.f, a2 = 0.f, a3 = 0.f;

#define YROW(mm) y[(((mm) & 0xFFFFFu) << 4) | (unsigned)t]
#define ACC4(dd) { a0 += __uint_as_float((dd).x << 16);          \
                   a1 += __uint_as_float((dd).x & 0xFFFF0000u);  \
                   a2 += __uint_as_float((dd).y << 16);          \
                   a3 += __uint_as_float((dd).y & 0xFFFF0000u); }

    for (int base = b; base < e; base += 64) {
        int idx = base + lane; if (idx > e - 1) idx = e - 1;
        unsigned meta = packed[idx];
        int cnt = e - base; if (cnt > 64) cnt = 64;
        int j = 0;
        for (; j + 16 <= cnt; j += 16) {
            unsigned mA = (unsigned)__shfl((int)meta, j + qt);
            unsigned mB = (unsigned)__shfl((int)meta, j + 4 + qt);
            unsigned mC = (unsigned)__shfl((int)meta, j + 8 + qt);
            unsigned mD = (unsigned)__shfl((int)meta, j + 12 + qt);
            uint2 dA = YROW(mA);
            uint2 dB = YROW(mB);
            uint2 dC = YROW(mC);
            uint2 dD = YROW(mD);
            ACC4(dA);
            ACC4(dB);
            ACC4(dC);
            ACC4(dD);
        }
        if (j + 8 <= cnt) {
            unsigned mA = (unsigned)__shfl((int)meta, j + qt);
            unsigned mB = (unsigned)__shfl((int)meta, j + 4 + qt);
            uint2 dA = YROW(mA);
            uint2 dB = YROW(mB);
            ACC4(dA);
            ACC4(dB);
            j += 8;
        }
        if (j + 4 <= cnt) {
            unsigned mm = (unsigned)__shfl((int)meta, j + qt);
            uint2 dd = YROW(mm);
            ACC4(dd);
            j += 4;
        }
        int rem = cnt - j;
        if (rem > 0) {
            unsigned mm = (unsigned)__shfl((int)meta, j + qt);  // clamped meta valid
            uint2 dd = YROW(mm);
            if (qt < rem) { ACC4(dd); }
        }
    }
#undef YROW
#undef ACC4

    // combine the 4 quarters (lanes t, t+16, t+32, t+48 hold same dims)
    a0 += __shfl_xor(a0, 16); a1 += __shfl_xor(a1, 16);
    a2 += __shfl_xor(a2, 16); a3 += __shfl_xor(a3, 16);
    a0 += __shfl_xor(a0, 32); a1 += __shfl_xor(a1, 32);
    a2 += __shfl_xor(a2, 32); a3 += __shfl_xor(a3, 32);

    float inv = 1.0f / fmaxf((float)(e - b), 1.0f);
    if (lane < 16) {
        uint2 o;
        o.x = pk2(a0 * inv, a1 * inv);
        o.y = pk2(a2 * inv, a3 * inv);
        hn[(size_t)n * 16 + t] = o;
    }
}

// Per-16-node-tile MFMA transform, both directions:
//   GEMM2 (transposed): h2^T = relu(Wlin @ [hd|hn]^T + blin)
//   GEMM3 (normal):     out  = h2 @ W2^T + b2
__global__ __launch_bounds__(256) void transform_both(
        const unsigned short* __restrict__ hn1, const unsigned short* __restrict__ hn2,
        const unsigned short* __restrict__ hi, const unsigned short* __restrict__ hu,
        const short* __restrict__ pWw, const short* __restrict__ pWwb,
        const float* __restrict__ bw, const float* __restrict__ bwb,
        const short* __restrict__ pVf, const short* __restrict__ pWf,
        const float* __restrict__ bv, const float* __restrict__ bf,
        float* __restrict__ item_out, float* __restrict__ user_out,
        int NI, int NU, int tilesI) {
    const int lane = threadIdx.x & 63;
    const int m = lane & 15, q = lane >> 4;
    int wave = (blockIdx.x * blockDim.x + threadIdx.x) >> 6;
    const bool dirU = wave >= tilesI;
    if (dirU) wave -= tilesI;
    const unsigned short* hn = dirU ? hn2 : hn1;
    const unsigned short* hd = dirU ? hu : hi;
    const short* pWlin = dirU ? pWwb : pWw;
    const float* blin  = dirU ? bwb : bw;
    const short* pW2   = dirU ? pWf : pVf;
    const float* b2    = dirU ? bf : bv;
    float* out = dirU ? user_out : item_out;
    const int N = dirU ? NU : NI;
    const int n0 = wave * 16;
    if (n0 >= N) return;
    int nrow = n0 + m; if (nrow > N - 1) nrow = N - 1;

    bf16x8 bH[2], bHN[2];
    {
        const unsigned short* ph = hd + (size_t)nrow * D + q * 8;
        bH[0] = *(const bf16x8*)(ph);
        bH[1] = *(const bf16x8*)(ph + 32);
        const unsigned short* pn = hn + (size_t)nrow * D + q * 8;
        bHN[0] = *(const bf16x8*)(pn);
        bHN[1] = *(const bf16x8*)(pn + 32);
    }

    f32x4 acc2[4] = {};
    #pragma unroll
    for (int it = 0; it < 4; ++it)
        #pragma unroll
        for (int kt = 0; kt < 4; ++kt) {
            bf16x8 a = *(const bf16x8*)(pWlin + (((it * 4) + kt) << 9) + (lane << 3));
            bf16x8 b = (kt < 2) ? bH[kt] : bHN[kt - 2];
            acc2[it] = __builtin_amdgcn_mfma_f32_16x16x32_bf16(a, b, acc2[it], 0, 0, 0);
        }

    const int srcA = ((q & 1) << 5) + m;
    const int srcB = srcA + 16;
    const bool hiq = (q >> 1) != 0;
    uint32_t u0[4], u1[4];
    float vbl = blin[lane];
    #pragma unroll
    for (int it = 0; it < 4; ++it) {
        float h0 = fmaxf(acc2[it][0] + __shfl(vbl, it * 16 + q * 4 + 0), 0.f);
        float h1 = fmaxf(acc2[it][1] + __shfl(vbl, it * 16 + q * 4 + 1), 0.f);
        float h2 = fmaxf(acc2[it][2] + __shfl(vbl, it * 16 + q * 4 + 2), 0.f);
        float h3 = fmaxf(acc2[it][3] + __shfl(vbl, it * 16 + q * 4 + 3), 0.f);
        u0[it] = pk2(h0, h1);
        u1[it] = pk2(h2, h3);
    }
    bf16x8 bA3[2];
    #pragma unroll
    for (int w = 0; w < 2; ++w) {
        uint32_t aa0 = (uint32_t)__shfl((int)u0[2*w],   srcA), bb0 = (uint32_t)__shfl((int)u0[2*w+1], srcA);
        uint32_t aa1 = (uint32_t)__shfl((int)u1[2*w],   srcA), bb1 = (uint32_t)__shfl((int)u1[2*w+1], srcA);
        uint32_t aa2 = (uint32_t)__shfl((int)u0[2*w],   srcB), bb2 = (uint32_t)__shfl((int)u0[2*w+1], srcB);
        uint32_t aa3 = (uint32_t)__shfl((int)u1[2*w],   srcB), bb3 = (uint32_t)__shfl((int)u1[2*w+1], srcB);
        FragU f;
        f.u[0] = hiq ? bb0 : aa0;
        f.u[1] = hiq ? bb1 : aa1;
        f.u[2] = hiq ? bb2 : aa2;
        f.u[3] = hiq ? bb3 : aa3;
        bA3[w] = f.v;
    }

    f32x4 acc3[4] = {};
    #pragma unroll
    for (int ct = 0; ct < 4; ++ct)
        #pragma unroll
        for (int kt = 0; kt < 2; ++kt) {
            bf16x8 b = *(const bf16x8*)(pW2 + (((ct * 2) + kt) << 9) + (lane << 3));
            acc3[ct] = __builtin_amdgcn_mfma_f32_16x16x32_bf16(bA3[kt], b, acc3[ct], 0, 0, 0);
        }
    #pragma unroll
    for (int ct = 0; ct < 4; ++ct) {
        float bb = b2[ct * 16 + m];
        #pragma unroll
        for (int rg = 0; rg < 4; ++rg) {
            int n = n0 + q * 4 + rg;
            if (n < N) out[(size_t)n * D + ct * 16 + m] = acc3[ct][rg] + bb;
        }
    }
}

extern "C" void kernel_launch(void* const* d_in, const int* in_sizes, int n_in,
                              void* d_out, int out_size, void* d_ws, size_t ws_size,
                              hipStream_t stream) {
    const int*   user_ids   = (const int*)  d_in[0];
    const int*   item_ids   = (const int*)  d_in[1];
    const int*   gender     = (const int*)  d_in[2];
    const int*   genres     = (const int*)  d_in[3];
    const int*   edge_user  = (const int*)  d_in[4];
    const int*   edge_item  = (const int*)  d_in[5];
    const int*   rating     = (const int*)  d_in[6];
    const float* user_emb   = (const float*)d_in[7];
    const float* item_emb   = (const float*)d_in[8];
    const float* gender_emb = (const float*)d_in[9];
    const float* genre_emb  = (const float*)d_in[10];
    const float* Wr_watched   = (const float*)d_in[11];
    const float* Wr_watchedby = (const float*)d_in[12];
    const float* Ww  = (const float*)d_in[13];
    const float* bw  = (const float*)d_in[14];
    const float* Wwb = (const float*)d_in[15];
    const float* bwb = (const float*)d_in[16];
    const float* Wf  = (const float*)d_in[17];
    const float* bf  = (const float*)d_in[18];
    const float* Vf  = (const float*)d_in[19];
    const float* bv  = (const float*)d_in[20];

    const int NU = in_sizes[0];
    const int NI = in_sizes[1];
    const int E  = in_sizes[4];
    const int NBI = (NI + 255) >> 8;   // coarse buckets (shift 8)
    const int NBU = (NU + 511) >> 9;   // coarse buckets (shift 9)

    float* out_f    = (float*)d_out;
    float* user_out = out_f;                       // [NU,64]
    float* item_out = out_f + (size_t)NU * D;      // [NI,64]

    // ws layout (bf16 first): hu, hi, hn1, hn2, y1, y2, packs, ints, staged x2
    unsigned short* hu  = (unsigned short*)d_ws;
    unsigned short* hi  = hu  + (size_t)NU * D;
    unsigned short* hn1 = hi  + (size_t)NI * D;            // items' agg
    unsigned short* hn2 = hn1 + (size_t)NI * D;            // users' agg
    unsigned short* y1  = hn2 + (size_t)NU * D;            // [6][NU][64]
    unsigned short* y2  = y1  + (size_t)NRAT * NU * D;     // [6][NI][64]
    size_t bfElems = (size_t)(2 * NU + 2 * NI) * D + (size_t)NRAT * (NU + NI) * D;
    size_t byteOff = (bfElems * 2 + 15) & ~(size_t)15;
    short* pWrW  = (short*)((char*)d_ws + byteOff);
    short* pWrWB = pWrW  + 24576;
    short* pWw   = pWrWB + 24576;
    short* pWwb  = pWw   + 8192;
    short* pVf   = pWwb  + 8192;
    short* pWf   = pVf   + 4096;
    int* coarseCntI = (int*)(pWf + 4096);   // 256, start of zeroRegion
    int* coarseCntU = coarseCntI + 256;     // 256, end of zeroRegion (512 ints)
    int* coarseOffI = coarseCntU + 256;     // 257
    int* coarseOffU = coarseOffI + 257;     // 257
    int* coarseCurI = coarseOffU + 257;     // 256
    int* coarseCurU = coarseCurI + 256;     // 256
    int* offI   = coarseCurU + 256;         // NI+1
    int* offU   = offI + NI + 1;            // NU+1
    unsigned* staged1 = (unsigned*)(offU + NU + 1);  // E
    unsigned* staged2 = staged1 + E;                 // E

    // 0. zero the coarse counters (2 KB)
    hipMemsetAsync(coarseCntI, 0, 512 * sizeof(int), stream);

    // 1. setup: node features + weight packing + edge histogram (1 dispatch)
    int totalh = (NU + NI) * 16;
    build_setup<<<(totalh + 255) / 256, 256, 0, stream>>>(
        user_ids, item_ids, gender, genres,
        user_emb, item_emb, gender_emb, genre_emb, hu, hi,
        edge_item, edge_user, coarseCntI, coarseCntU, E,
        Wr_watched, Wr_watchedby, Ww, Wwb, Vf, Wf,
        pWrW, pWrWB, pWw, pWwb, pVf, pWf, NU, NI);

    // 2. coarse scan
    scan_both<<<2, 256, 0, stream>>>(coarseCntI, coarseCntU, coarseOffI, coarseOffU,
                                     coarseCurI, coarseCurU, NBI, NBU, E);

    // 3. sort pass A (both dirs, TILE_A) + pretransform (hidden) in one launch
    const int nTilesA = (E + TILE_A - 1) / TILE_A;
    const int wavesU = (NU + 15) / 16, wavesI = (NI + 15) / 16;
    const int ptBlocks = (wavesU + wavesI + 3) / 4;
    msA_pre<<<2 * nTilesA + ptBlocks, 256, 0, stream>>>(
        edge_item, edge_user, rating, coarseCurI, coarseCurU, staged1, staged2,
        hu, hi, pWrW, pWrWB, y1, y2, E, nTilesA, NU, NI, wavesU);

    // 4. sort pass B (both dirs)
    multisplit_B2<<<NBI + NBU, 256, 0, stream>>>(staged1, staged2, coarseOffI, coarseOffU,
                                                 offI, offU, NBI, NU, NI, E);

    // 5. gather both, transform both
    gather_both<<<(NI + NU + 3) / 4, 256, 0, stream>>>(offI, offU, staged1, staged2,
                                                       (const uint2*)y1, (const uint2*)y2,
                                                       (uint2*)hn1, (uint2*)hn2, NI, NU);
    {
        int tilesI = (NI + 15) / 16, tilesU = (NU + 15) / 16;
        int blocks = (tilesI + tilesU + 3) / 4;
        transform_both<<<blocks, 256, 0, stream>>>(hn1, hn2, hi, hu, pWw, pWwb, bw, bwb,
                                                   pVf, pWf, bv, bf, item_out, user_out,
                                                   NI, NU, tilesI);
    }
}